// Round 12
// baseline (3599.759 us; speedup 1.0000x reference)
//
#include <hip/hip_runtime.h>

#define BB 16
#define LL 512
#define DD 128
#define CH 32
#define NCH (LL / CH)

// 8-lane all-reduce sum (lanes within a DPP half-row), pure VALU:
// quad xor1, quad xor2, then half-row mirror pairs the two quads.
__device__ __forceinline__ float red8(float v) {
    v += __int_as_float(__builtin_amdgcn_update_dpp(
            0, __float_as_int(v), 0xB1, 0xF, 0xF, true));
    v += __int_as_float(__builtin_amdgcn_update_dpp(
            0, __float_as_int(v), 0x4E, 0xF, 0xF, true));
    v += __int_as_float(__builtin_amdgcn_update_dpp(
            0, __float_as_int(v), 0x141, 0xF, 0xF, true));
    return v;
}

#define SCAN_REGS __attribute__((amdgpu_waves_per_eu(2, 2)))

// ---------------- transpose Wq, Wk, Wout (once per call, tiny) ----------------
__global__ void transpose3_kernel(const float* __restrict__ Wq,
                                  const float* __restrict__ Wk,
                                  const float* __restrict__ Wout,
                                  float* __restrict__ WqT,
                                  float* __restrict__ WkT,
                                  float* __restrict__ WoutT) {
    const float* src; float* dst;
    if (blockIdx.x == 0)      { src = Wq;   dst = WqT;   }
    else if (blockIdx.x == 1) { src = Wk;   dst = WkT;   }
    else                      { src = Wout; dst = WoutT; }
    for (int idx = threadIdx.x; idx < DD * DD; idx += blockDim.x) {
        int r = idx >> 7, c = idx & 127;
        dst[c * DD + r] = src[idx];
    }
}

// ---------------- prologue: q/k projections, k-normalize, P0 rotation, poly ----
__global__ __launch_bounds__(128) void prologue_kernel(
        const float* __restrict__ x, const float* __restrict__ WqT,
        const float* __restrict__ WkT, const float* __restrict__ P0,
        const float* __restrict__ log_gain, const float* __restrict__ coeffs,
        float* __restrict__ kphi, float* __restrict__ qphi) {
    const int row0 = blockIdx.x * 4;
    const int e = threadIdx.x;
    __shared__ float xs[4][DD];
    __shared__ float qrow[4][DD];
    __shared__ float wred[4][2];

    #pragma unroll
    for (int rr = 0; rr < 4; ++rr)
        xs[rr][e] = x[(size_t)(row0 + rr) * DD + e];
    __syncthreads();

    float aq[4] = {0,0,0,0}, ak[4] = {0,0,0,0};
    #pragma unroll 4
    for (int d = 0; d < DD; ++d) {
        float wq = WqT[d * DD + e];
        float wk = WkT[d * DD + e];
        #pragma unroll
        for (int rr = 0; rr < 4; ++rr) {
            float xv = xs[rr][d];
            aq[rr] = fmaf(xv, wq, aq[rr]);
            ak[rr] = fmaf(xv, wk, ak[rr]);
        }
    }
    const int lane = threadIdx.x & 63, wv = threadIdx.x >> 6;
    #pragma unroll
    for (int rr = 0; rr < 4; ++rr) {
        float s = ak[rr] * ak[rr];
        #pragma unroll
        for (int m = 1; m <= 32; m <<= 1) s += __shfl_xor(s, m);
        if (lane == 0) wred[rr][wv] = s;
    }
    __syncthreads();
    const float c0 = coeffs[0], c1v = coeffs[1];
    #pragma unroll
    for (int rr = 0; rr < 4; ++rr) {
        float s = wred[rr][0] + wred[rr][1];
        float kn = ak[rr] / fmaxf(sqrtf(s), 1e-12f);
        kphi[(size_t)(row0 + rr) * DD + e] = c0 * kn + c1v * kn * kn;
        qrow[rr][e] = aq[rr];
    }
    __syncthreads();
    float acc[4] = {0,0,0,0};
    #pragma unroll 4
    for (int d = 0; d < DD; ++d) {
        float pv = P0[d * DD + e];
        #pragma unroll
        for (int rr = 0; rr < 4; ++rr) acc[rr] = fmaf(qrow[rr][d], pv, acc[rr]);
    }
    const float g = expf(log_gain[e]);
    #pragma unroll
    for (int rr = 0; rr < 4; ++rr) {
        float qa = tanhf(g * acc[rr]);
        qphi[(size_t)(row0 + rr) * DD + e] = c0 * qa + c1v * qa * qa;
    }
}

// component select helpers (fold at compile time under full unroll)
#define CSEL(l, q0, q1) ((l) == 0 ? (q0).x : (l) == 1 ? (q0).z : (l) == 2 ? (q1).x : (q1).z)
#define CSEL2(l, q0, q1) ((l) == 0 ? (q0).y : (l) == 1 ? (q0).w : (l) == 2 ? (q1).y : (q1).w)
#define K4C(l, v) ((l) == 0 ? (v).x : (l) == 1 ? (v).y : (l) == 2 ? (v).z : (v).w)

// ---------------- main sequential scan: one block per batch --------------------
// R8 champion structure (chunked LDS staging, vmem-free per-step barriers,
// single accumulators, qq in phase 6) with three pressure-neutral cuts:
//  (1) direct float4-component arithmetic — no scalar unpack arrays (kills
//      candidate v_mov bloat; fma order identical to R8 -> bit-identical);
//  (2) interleaved (u,p) and (w,h) LDS vectors — one b128 write per writer,
//      reads remain 2-way-bank-aliased (free);
//  (3) CH=32 — half the chunk-boundary drains; staging split across sl=0/1
//      keeps the in-flight register spike at R8's level. LDS ~118 KB.
// Thread (g = tid>>3, j = tid&7): rows {2g,2g+1}; interleaved column set
// col(m,l) = 4j + 32m + l. A = S S^T S via exact rank-3 recurrence; ||S||_F^2
// via scalar recurrence.
__global__ SCAN_REGS __launch_bounds__(512)
void scan_kernel(
        const float* __restrict__ kphi, const float* __restrict__ qphi,
        const float* __restrict__ x, const float* __restrict__ M0,
        const float* __restrict__ S0, float* __restrict__ ys) {
    const int b    = blockIdx.x;
    const int tid  = threadIdx.x;
    const int j    = tid & 7;
    const int g    = tid >> 3;
    const int r0   = 2 * g;
    const int w    = tid >> 6;
    const int lane = tid & 63;

    __shared__ __align__(16) float kc[2][CH * DD];
    __shared__ __align__(16) float qc[2][CH * DD];
    __shared__ __align__(16) float xc[2][CH * DD];
    __shared__ __align__(16) float yc[CH * DD];
    __shared__ __align__(16) float usps[2 * DD];   // (u,p) interleaved by column
    __shared__ __align__(16) float whs[2 * DD];    // (w,h) interleaved by column
    __shared__ float red[64];
    __shared__ float n2sh;

    float S[32], ST[32], A[32], M[32];
    {
        const float4* S04 = (const float4*)S0;
        const float4* M04 = (const float4*)M0;
        #pragma unroll
        for (int rl = 0; rl < 2; ++rl)
            #pragma unroll
            for (int m = 0; m < 4; ++m) {
                int f4 = (r0 + rl) * 32 + j + 8 * m;
                float4 s4 = S04[f4], m4 = M04[f4];
                int i = rl * 16 + 4 * m;
                S[i+0] = s4.x; S[i+1] = s4.y; S[i+2] = s4.z; S[i+3] = s4.w;
                M[i+0] = m4.x; M[i+1] = m4.y; M[i+2] = m4.z; M[i+3] = m4.w;
            }
        #pragma unroll
        for (int rl = 0; rl < 2; ++rl)
            #pragma unroll
            for (int m = 0; m < 4; ++m)
                #pragma unroll
                for (int l = 0; l < 4; ++l)
                    ST[rl*16 + 4*m + l] =
                        S0[(size_t)(4*j + 32*m + l) * DD + r0 + rl];
        #pragma unroll
        for (int i = 0; i < 32; ++i) A[i] = 0.f;   // exact when S0 == 0
    }

    // ||S0||^2 block reduction
    float sp = 0.f;
    #pragma unroll
    for (int i = 0; i < 32; ++i) sp = fmaf(S[i], S[i], sp);
    sp = red8(sp);
    if (j == 0) red[g] = sp;

    const size_t base = (size_t)b * LL * DD;

    // preload chunk 0 (each wave copies 6 x 1KB segments; 16 segs per array)
    #pragma unroll
    for (int i = 0; i < 6; ++i) {
        int seg = w * 6 + i, arr = seg >> 4, sub = seg & 15;
        const float* sp0 = (arr == 0 ? kphi : (arr == 1 ? qphi : x))
                           + base + sub * 256 + lane * 4;
        float* dp = (arr == 0 ? kc[0] : (arr == 1 ? qc[0] : xc[0]))
                    + sub * 256 + lane * 4;
        *(float4*)dp = *(const float4*)sp0;
    }
    __syncthreads();
    if (tid < 64) {
        float s = red[tid];
        #pragma unroll
        for (int m = 1; m <= 32; m <<= 1) s += __shfl_xor(s, m);
        if (tid == 0) n2sh = s;
    }
    __syncthreads();
    float n2 = n2sh;

    const float a = 0.9f, a2v = 0.81f, a3v = 0.729f;

    #pragma unroll 1
    for (int tc = 0; tc < NCH; ++tc) {
        const int cb = tc & 1;
        const float* kcb = kc[cb];
        const float* qcb = qc[cb];
        const float* xcb = xc[cb];

        #pragma unroll 1
        for (int sl = 0; sl < CH; ++sl) {
            const int so = sl * DD;

            // staging for next chunk: 3 segs at sl==0, 3 at sl==1
            float4 pre0, pre1, pre2;
            const bool doPre = (sl < 2) && (tc + 1 < NCH);
            if (doPre) {
                const size_t nbg = base + (size_t)(tc + 1) * CH * DD;
                const int sbase = w * 6 + sl * 3;
                {
                    int seg = sbase + 0, arr = seg >> 4, sub = seg & 15;
                    pre0 = *(const float4*)((arr == 0 ? kphi : (arr == 1 ? qphi : x))
                                            + nbg + sub * 256 + lane * 4);
                }
                {
                    int seg = sbase + 1, arr = seg >> 4, sub = seg & 15;
                    pre1 = *(const float4*)((arr == 0 ? kphi : (arr == 1 ? qphi : x))
                                            + nbg + sub * 256 + lane * 4);
                }
                {
                    int seg = sbase + 2, arr = seg >> 4, sub = seg & 15;
                    pre2 = *(const float4*)((arr == 0 ? kphi : (arr == 1 ? qphi : x))
                                            + nbg + sub * 256 + lane * 4);
                }
            }

            // ---- phase 2 (row side): pred = M k, p = S v, cv = v.v ----
            float4 kk4[4];
            {
                const float4* k4 = (const float4*)(kcb + so);
                #pragma unroll
                for (int m = 0; m < 4; ++m) kk4[m] = k4[j + 8 * m];
            }
            float pr0 = 0.f, pr1 = 0.f, pp0 = 0.f, pp1 = 0.f, cvp = 0.f;
            #pragma unroll
            for (int m = 0; m < 4; ++m)
                #pragma unroll
                for (int l = 0; l < 4; ++l) {
                    int i = 4 * m + l;
                    float kv = K4C(l, kk4[m]);
                    pr0 = fmaf(M[i],      kv, pr0);
                    pr1 = fmaf(M[16 + i], kv, pr1);
                    pp0 = fmaf(S[i],      kv, pp0);
                    pp1 = fmaf(S[16 + i], kv, pp1);
                    cvp = fmaf(kv, kv, cvp);
                }
            pr0 = red8(pr0); pr1 = red8(pr1);
            pp0 = red8(pp0); pp1 = red8(pp1);
            const float cv = red8(cvp);
            const float2 xv = *(const float2*)&xcb[so + r0];
            const float u0 = pr0 - xv.x, u1 = pr1 - xv.y;
            const float p0 = pp0, p1 = pp1;
            if (j == 0) {
                float4 up; up.x = u0; up.y = p0; up.z = u1; up.w = p1;
                *(float4*)&usps[2 * r0] = up;      // words 4g (16B aligned)
            }
            __syncthreads();                               // barrier 1 (LDS only)

            // ---- phase 4 (col side): w = S^T u, h = S^T p, dots; ST update ----
            const float2 vc = *(const float2*)&kcb[so + r0];
            float w0 = 0.f, w1 = 0.f, h0 = 0.f, h1 = 0.f, cuup = 0.f, cupp = 0.f;
            {
                const float4* up4 = (const float4*)usps;
                #pragma unroll
                for (int m = 0; m < 4; ++m) {
                    float4 q0 = up4[2 * j + 16 * m];
                    float4 q1 = up4[2 * j + 16 * m + 1];
                    #pragma unroll
                    for (int l = 0; l < 4; ++l) {
                        int i = 4 * m + l;
                        float uv = CSEL(l, q0, q1);
                        float pv = CSEL2(l, q0, q1);
                        float st0 = ST[i], st1 = ST[16 + i];
                        w0 = fmaf(st0, uv, w0);  w1 = fmaf(st1, uv, w1);
                        h0 = fmaf(st0, pv, h0);  h1 = fmaf(st1, pv, h1);
                        cuup = fmaf(uv, uv, cuup);
                        cupp = fmaf(uv, pv, cupp);
                        ST[i]      = fmaf(a, st0, vc.x * uv);  // old st above only
                        ST[16 + i] = fmaf(a, st1, vc.y * uv);
                    }
                }
            }
            w0 = red8(w0); w1 = red8(w1); h0 = red8(h0); h1 = red8(h1);
            const float cu  = red8(cuup);
            const float cup = red8(cupp);
            n2 = a2v * n2 + 2.0f * a * cup + cu * cv;      // ||S_t||_F^2 recurrence
            if (j == 0) {
                float4 wh; wh.x = w0; wh.y = h0; wh.z = w1; wh.w = h1;
                *(float4*)&whs[2 * r0] = wh;
            }
            // commit staged segs to the other LDS buffer
            if (doPre) {
                float* kn = kc[cb ^ 1]; float* qn = qc[cb ^ 1]; float* xn = xc[cb ^ 1];
                const int sbase = w * 6 + sl * 3;
                {
                    int seg = sbase + 0, arr = seg >> 4, sub = seg & 15;
                    *(float4*)((arr == 0 ? kn : (arr == 1 ? qn : xn))
                               + sub * 256 + lane * 4) = pre0;
                }
                {
                    int seg = sbase + 1, arr = seg >> 4, sub = seg & 15;
                    *(float4*)((arr == 0 ? kn : (arr == 1 ? qn : xn))
                               + sub * 256 + lane * 4) = pre1;
                }
                {
                    int seg = sbase + 2, arr = seg >> 4, sub = seg & 15;
                    *(float4*)((arr == 0 ? kn : (arr == 1 ? qn : xn))
                               + sub * 256 + lane * 4) = pre2;
                }
            }
            __syncthreads();                               // barrier 2 (LDS only*)

            // ---- phase 6 (row side): g = S w; rank-3 A; S, M updates; y = M q ----
            float4 wh0[4], wh1[4], qq4[4];
            {
                const float4* wh4 = (const float4*)whs;
                const float4* q4  = (const float4*)(qcb + so);
                #pragma unroll
                for (int m = 0; m < 4; ++m) {
                    wh0[m] = wh4[2 * j + 16 * m];
                    wh1[m] = wh4[2 * j + 16 * m + 1];
                    qq4[m] = q4[j + 8 * m];
                }
            }
            float g0 = 0.f, g1 = 0.f;
            #pragma unroll
            for (int m = 0; m < 4; ++m)
                #pragma unroll
                for (int l = 0; l < 4; ++l) {
                    int i = 4 * m + l;
                    float wv = CSEL(l, wh0[m], wh1[m]);
                    g0 = fmaf(S[i],      wv, g0);
                    g1 = fmaf(S[16 + i], wv, g1);
                }
            g0 = red8(g0); g1 = red8(g1);

            const float rho0 = a2v * g0 + a * cu * p0 + (a * cup + cv * cu) * u0;
            const float rho1 = a2v * g1 + a * cu * p1 + (a * cup + cv * cu) * u1;
            const float sg0  = a2v * p0 + a * cv * u0;
            const float sg1  = a2v * p1 + a * cv * u1;
            const float ta0  = a2v * u0, ta1 = a2v * u1;
            const float nrm  = sqrtf(fmaxf(n2, 0.f)) + 1e-6f;
            const float rn   = 1.0f / nrm;
            const float c1   = -0.015f * rn;    // 0.99M - 0.01*(1.5 S/n - 0.5 A/n^3)
            const float c2   = 0.005f * rn * rn * rn;

            float y0 = 0.f, y1 = 0.f;
            #pragma unroll
            for (int m = 0; m < 4; ++m)
                #pragma unroll
                for (int l = 0; l < 4; ++l) {
                    int i = 4 * m + l;
                    float kv = K4C(l, kk4[m]);
                    float wv = CSEL(l, wh0[m], wh1[m]);
                    float hv = CSEL2(l, wh0[m], wh1[m]);
                    float qv = K4C(l, qq4[m]);
                    S[i]      = fmaf(a, S[i],      u0 * kv);
                    S[16 + i] = fmaf(a, S[16 + i], u1 * kv);
                    A[i]      = fmaf(a3v, A[i],
                                     fmaf(rho0, kv, fmaf(sg0, wv, ta0 * hv)));
                    A[16 + i] = fmaf(a3v, A[16 + i],
                                     fmaf(rho1, kv, fmaf(sg1, wv, ta1 * hv)));
                    M[i]      = fmaf(0.99f, M[i],      fmaf(c1, S[i],      c2 * A[i]));
                    M[16 + i] = fmaf(0.99f, M[16 + i], fmaf(c1, S[16 + i], c2 * A[16 + i]));
                    y0 = fmaf(M[i],      qv, y0);
                    y1 = fmaf(M[16 + i], qv, y1);
                }
            y0 = red8(y0); y1 = red8(y1);
            if (j == 0)
                *(float2*)&yc[so + r0] = make_float2(y0, y1);
        }

        // chunk end: flush yc -> ys (two float4 per thread at CH=32)
        __syncthreads();
        #pragma unroll
        for (int f = 0; f < 2; ++f) {
            int idx = tid + f * 512;
            float4 yv = *(float4*)&yc[idx * 4];
            *(float4*)(ys + base + (size_t)tc * CH * DD + idx * 4) = yv;
        }
    }
}

// ---------------- epilogue: out = ys @ Wout^T + bout ---------------------------
__global__ __launch_bounds__(128) void epilogue_kernel(
        const float* __restrict__ ys, const float* __restrict__ WoutT,
        const float* __restrict__ bout, float* __restrict__ out) {
    const int row0 = blockIdx.x * 4;
    const int e = threadIdx.x;
    __shared__ float yr[4][DD];
    #pragma unroll
    for (int rr = 0; rr < 4; ++rr)
        yr[rr][e] = ys[(size_t)(row0 + rr) * DD + e];
    __syncthreads();
    float acc[4] = {0,0,0,0};
    #pragma unroll 4
    for (int d = 0; d < DD; ++d) {
        float w = WoutT[d * DD + e];
        #pragma unroll
        for (int rr = 0; rr < 4; ++rr) acc[rr] = fmaf(yr[rr][d], w, acc[rr]);
    }
    const float bo = bout[e];
    #pragma unroll
    for (int rr = 0; rr < 4; ++rr)
        out[(size_t)(row0 + rr) * DD + e] = acc[rr] + bo;
}

extern "C" void kernel_launch(void* const* d_in, const int* in_sizes, int n_in,
                              void* d_out, int out_size, void* d_ws, size_t ws_size,
                              hipStream_t stream) {
    const float* x        = (const float*)d_in[0];
    const float* Wq       = (const float*)d_in[1];
    const float* Wk       = (const float*)d_in[2];
    const float* P0       = (const float*)d_in[3];
    const float* M0       = (const float*)d_in[4];
    const float* S0       = (const float*)d_in[5];
    const float* log_gain = (const float*)d_in[6];
    const float* coeffs   = (const float*)d_in[7];
    const float* Wout     = (const float*)d_in[8];
    const float* bout     = (const float*)d_in[9];
    float* out = (float*)d_out;

    float* ws    = (float*)d_ws;
    float* WqT   = ws;                      // 16384
    float* WkT   = ws + 16384;              // 16384
    float* WoutT = ws + 32768;              // 16384
    float* kphi  = ws + 49152;              // B*L*D each below
    float* qphi  = kphi + (size_t)BB * LL * DD;
    float* ysb   = qphi + (size_t)BB * LL * DD;

    hipLaunchKernelGGL(transpose3_kernel, dim3(3), dim3(256), 0, stream,
                       Wq, Wk, Wout, WqT, WkT, WoutT);
    hipLaunchKernelGGL(prologue_kernel, dim3(BB * LL / 4), dim3(128), 0, stream,
                       x, WqT, WkT, P0, log_gain, coeffs, kphi, qphi);
    hipLaunchKernelGGL(scan_kernel, dim3(BB), dim3(512), 0, stream,
                       kphi, qphi, x, M0, S0, ysb);
    hipLaunchKernelGGL(epilogue_kernel, dim3(BB * LL / 4), dim3(128), 0, stream,
                       ysb, WoutT, bout, out);
}

// Round 13
// 2038.411 us; speedup vs baseline: 1.7660x; 1.7660x over previous
//
#include <hip/hip_runtime.h>

#define BB 16
#define LL 512
#define DD 128
#define CH 16
#define NCH (LL / CH)

// 8-lane all-reduce sum (lanes within a DPP half-row), pure VALU:
// quad xor1, quad xor2, then half-row mirror pairs the two quads.
__device__ __forceinline__ float red8(float v) {
    v += __int_as_float(__builtin_amdgcn_update_dpp(
            0, __float_as_int(v), 0xB1, 0xF, 0xF, true));
    v += __int_as_float(__builtin_amdgcn_update_dpp(
            0, __float_as_int(v), 0x4E, 0xF, 0xF, true));
    v += __int_as_float(__builtin_amdgcn_update_dpp(
            0, __float_as_int(v), 0x141, 0xF, 0xF, true));
    return v;
}

#define SCAN_REGS __attribute__((amdgpu_waves_per_eu(2, 2)))

// ---------------- transpose Wq, Wk, Wout (once per call, tiny) ----------------
__global__ void transpose3_kernel(const float* __restrict__ Wq,
                                  const float* __restrict__ Wk,
                                  const float* __restrict__ Wout,
                                  float* __restrict__ WqT,
                                  float* __restrict__ WkT,
                                  float* __restrict__ WoutT) {
    const float* src; float* dst;
    if (blockIdx.x == 0)      { src = Wq;   dst = WqT;   }
    else if (blockIdx.x == 1) { src = Wk;   dst = WkT;   }
    else                      { src = Wout; dst = WoutT; }
    for (int idx = threadIdx.x; idx < DD * DD; idx += blockDim.x) {
        int r = idx >> 7, c = idx & 127;
        dst[c * DD + r] = src[idx];
    }
}

// ---------------- prologue: q/k projections, k-normalize, P0 rotation, poly ----
__global__ __launch_bounds__(128) void prologue_kernel(
        const float* __restrict__ x, const float* __restrict__ WqT,
        const float* __restrict__ WkT, const float* __restrict__ P0,
        const float* __restrict__ log_gain, const float* __restrict__ coeffs,
        float* __restrict__ kphi, float* __restrict__ qphi) {
    const int row0 = blockIdx.x * 4;
    const int e = threadIdx.x;
    __shared__ float xs[4][DD];
    __shared__ float qrow[4][DD];
    __shared__ float wred[4][2];

    #pragma unroll
    for (int rr = 0; rr < 4; ++rr)
        xs[rr][e] = x[(size_t)(row0 + rr) * DD + e];
    __syncthreads();

    float aq[4] = {0,0,0,0}, ak[4] = {0,0,0,0};
    #pragma unroll 4
    for (int d = 0; d < DD; ++d) {
        float wq = WqT[d * DD + e];
        float wk = WkT[d * DD + e];
        #pragma unroll
        for (int rr = 0; rr < 4; ++rr) {
            float xv = xs[rr][d];
            aq[rr] = fmaf(xv, wq, aq[rr]);
            ak[rr] = fmaf(xv, wk, ak[rr]);
        }
    }
    const int lane = threadIdx.x & 63, wv = threadIdx.x >> 6;
    #pragma unroll
    for (int rr = 0; rr < 4; ++rr) {
        float s = ak[rr] * ak[rr];
        #pragma unroll
        for (int m = 1; m <= 32; m <<= 1) s += __shfl_xor(s, m);
        if (lane == 0) wred[rr][wv] = s;
    }
    __syncthreads();
    const float c0 = coeffs[0], c1v = coeffs[1];
    #pragma unroll
    for (int rr = 0; rr < 4; ++rr) {
        float s = wred[rr][0] + wred[rr][1];
        float kn = ak[rr] / fmaxf(sqrtf(s), 1e-12f);
        kphi[(size_t)(row0 + rr) * DD + e] = c0 * kn + c1v * kn * kn;
        qrow[rr][e] = aq[rr];
    }
    __syncthreads();
    float acc[4] = {0,0,0,0};
    #pragma unroll 4
    for (int d = 0; d < DD; ++d) {
        float pv = P0[d * DD + e];
        #pragma unroll
        for (int rr = 0; rr < 4; ++rr) acc[rr] = fmaf(qrow[rr][d], pv, acc[rr]);
    }
    const float g = expf(log_gain[e]);
    #pragma unroll
    for (int rr = 0; rr < 4; ++rr) {
        float qa = tanhf(g * acc[rr]);
        qphi[(size_t)(row0 + rr) * DD + e] = c0 * qa + c1v * qa * qa;
    }
}

// ---------------- main sequential scan: one block per batch --------------------
// R8 CHAMPION, verbatim. 512 threads, chunked LDS staging: k/q/x bulk-copied
// into LDS in 16-step double-buffered chunks; ys buffered in LDS and flushed
// once per chunk -> steady-state per-step barriers have NO outstanding vmem,
// so the compiler's mandatory `s_waitcnt vmcnt(0)` before each s_barrier is
// free. Thread (g = tid>>3, j = tid&7): rows {2g,2g+1}; interleaved column
// set col(m,l) = 4j + 32m + l (float4s {j+8m}) -> unpadded LDS vector reads
// are conflict-free. ST holds the transpose tile for the same index
// partition. 8-lane DPP butterflies for all reductions. A = S S^T S via exact
// rank-3 recurrence; ||S||_F^2 via scalar recurrence.
// DO NOT raise peak liveness: this kernel sits at the 128-arch-VGPR edge.
// R9 (reg prefetch), R10 (split accumulators), R12 (held float4s/CSEL) each
// regressed 19-80% by adding/rigidifying live ranges. Allocator knobs
// (launch_bounds, waves_per_eu, agpr_alloc, LDS forcing) never move VGPR off
// 128 — tested R5/R6/R7/R9/R11.
__global__ SCAN_REGS __launch_bounds__(512)
void scan_kernel(
        const float* __restrict__ kphi, const float* __restrict__ qphi,
        const float* __restrict__ x, const float* __restrict__ M0,
        const float* __restrict__ S0, float* __restrict__ ys) {
    const int b    = blockIdx.x;
    const int tid  = threadIdx.x;
    const int j    = tid & 7;
    const int g    = tid >> 3;
    const int r0   = 2 * g;
    const int w    = tid >> 6;
    const int lane = tid & 63;

    __shared__ __align__(16) float kc[2][CH * DD];
    __shared__ __align__(16) float qc[2][CH * DD];
    __shared__ __align__(16) float xc[2][CH * DD];
    __shared__ __align__(16) float yc[CH * DD];
    __shared__ __align__(16) float us[DD], ps[DD], wsv[DD], hs[DD];
    __shared__ float red[64];
    __shared__ float n2sh;

    float S[32], ST[32], A[32], M[32];
    {
        const float4* S04 = (const float4*)S0;
        const float4* M04 = (const float4*)M0;
        #pragma unroll
        for (int rl = 0; rl < 2; ++rl)
            #pragma unroll
            for (int m = 0; m < 4; ++m) {
                int f4 = (r0 + rl) * 32 + j + 8 * m;
                float4 s4 = S04[f4], m4 = M04[f4];
                int i = rl * 16 + 4 * m;
                S[i+0] = s4.x; S[i+1] = s4.y; S[i+2] = s4.z; S[i+3] = s4.w;
                M[i+0] = m4.x; M[i+1] = m4.y; M[i+2] = m4.z; M[i+3] = m4.w;
            }
        #pragma unroll
        for (int rl = 0; rl < 2; ++rl)
            #pragma unroll
            for (int m = 0; m < 4; ++m)
                #pragma unroll
                for (int l = 0; l < 4; ++l)
                    ST[rl*16 + 4*m + l] =
                        S0[(size_t)(4*j + 32*m + l) * DD + r0 + rl];
        #pragma unroll
        for (int i = 0; i < 32; ++i) A[i] = 0.f;   // exact when S0 == 0
    }

    // ||S0||^2 block reduction
    float sp = 0.f;
    #pragma unroll
    for (int i = 0; i < 32; ++i) sp = fmaf(S[i], S[i], sp);
    sp = red8(sp);
    if (j == 0) red[g] = sp;

    const size_t base = (size_t)b * LL * DD;

    // preload chunk 0 (each wave copies 3 x 1KB segments)
    #pragma unroll
    for (int i = 0; i < 3; ++i) {
        int seg = w * 3 + i, arr = seg >> 3, sub = seg & 7;
        const float* sp0 = (arr == 0 ? kphi : (arr == 1 ? qphi : x))
                           + base + sub * 256 + lane * 4;
        float* dp = (arr == 0 ? kc[0] : (arr == 1 ? qc[0] : xc[0]))
                    + sub * 256 + lane * 4;
        *(float4*)dp = *(const float4*)sp0;
    }
    __syncthreads();
    if (tid < 64) {
        float s = red[tid];
        #pragma unroll
        for (int m = 1; m <= 32; m <<= 1) s += __shfl_xor(s, m);
        if (tid == 0) n2sh = s;
    }
    __syncthreads();
    float n2 = n2sh;

    const float a = 0.9f, a2v = 0.81f, a3v = 0.729f;

    #pragma unroll 1
    for (int tc = 0; tc < NCH; ++tc) {
        const int cb = tc & 1;
        const float* kcb = kc[cb];
        const float* qcb = qc[cb];
        const float* xcb = xc[cb];

        #pragma unroll 1
        for (int sl = 0; sl < CH; ++sl) {
            const int so = sl * DD;

            // issue next-chunk staging loads at chunk start (drained ~1x/chunk)
            float4 pre0, pre1, pre2;
            const bool doPre = (sl == 0) && (tc + 1 < NCH);
            if (doPre) {
                const size_t nbg = base + (size_t)(tc + 1) * CH * DD;
                {
                    int seg = w * 3 + 0, arr = seg >> 3, sub = seg & 7;
                    pre0 = *(const float4*)((arr == 0 ? kphi : (arr == 1 ? qphi : x))
                                            + nbg + sub * 256 + lane * 4);
                }
                {
                    int seg = w * 3 + 1, arr = seg >> 3, sub = seg & 7;
                    pre1 = *(const float4*)((arr == 0 ? kphi : (arr == 1 ? qphi : x))
                                            + nbg + sub * 256 + lane * 4);
                }
                {
                    int seg = w * 3 + 2, arr = seg >> 3, sub = seg & 7;
                    pre2 = *(const float4*)((arr == 0 ? kphi : (arr == 1 ? qphi : x))
                                            + nbg + sub * 256 + lane * 4);
                }
            }

            // ---- phase 2 (row side): pred = M k, p = S v, cv = v.v ----
            float kk[16];
            {
                const float4* k4 = (const float4*)(kcb + so);
                #pragma unroll
                for (int m = 0; m < 4; ++m) {
                    float4 v4 = k4[j + 8 * m];
                    kk[4*m+0] = v4.x; kk[4*m+1] = v4.y;
                    kk[4*m+2] = v4.z; kk[4*m+3] = v4.w;
                }
            }
            float pr0 = 0.f, pr1 = 0.f, pp0 = 0.f, pp1 = 0.f, cvp = 0.f;
            #pragma unroll
            for (int cl = 0; cl < 16; ++cl) {
                float kv = kk[cl];
                pr0 = fmaf(M[cl],      kv, pr0);
                pr1 = fmaf(M[16 + cl], kv, pr1);
                pp0 = fmaf(S[cl],      kv, pp0);
                pp1 = fmaf(S[16 + cl], kv, pp1);
                cvp = fmaf(kv, kv, cvp);
            }
            pr0 = red8(pr0); pr1 = red8(pr1);
            pp0 = red8(pp0); pp1 = red8(pp1);
            const float cv = red8(cvp);
            const float2 xv = *(const float2*)&xcb[so + r0];
            const float u0 = pr0 - xv.x, u1 = pr1 - xv.y;
            const float p0 = pp0, p1 = pp1;
            if (j == 0) {
                *(float2*)&us[r0] = make_float2(u0, u1);
                *(float2*)&ps[r0] = make_float2(p0, p1);
            }
            __syncthreads();                               // barrier 1 (LDS only)

            // ---- phase 4 (col side): w = S^T u, h = S^T p, dots; ST update ----
            float uu[16], pa[16];
            {
                const float4* u4 = (const float4*)us;
                const float4* p4 = (const float4*)ps;
                #pragma unroll
                for (int m = 0; m < 4; ++m) {
                    float4 a4 = u4[j + 8 * m], b4 = p4[j + 8 * m];
                    uu[4*m+0] = a4.x; uu[4*m+1] = a4.y;
                    uu[4*m+2] = a4.z; uu[4*m+3] = a4.w;
                    pa[4*m+0] = b4.x; pa[4*m+1] = b4.y;
                    pa[4*m+2] = b4.z; pa[4*m+3] = b4.w;
                }
            }
            const float2 vc = *(const float2*)&kcb[so + r0];
            float w0 = 0.f, w1 = 0.f, h0 = 0.f, h1 = 0.f, cuup = 0.f, cupp = 0.f;
            #pragma unroll
            for (int cl = 0; cl < 16; ++cl) {
                float uv = uu[cl], pv = pa[cl];
                float st0 = ST[cl], st1 = ST[16 + cl];
                w0 = fmaf(st0, uv, w0);  w1 = fmaf(st1, uv, w1);
                h0 = fmaf(st0, pv, h0);  h1 = fmaf(st1, pv, h1);
                cuup = fmaf(uv, uv, cuup);
                cupp = fmaf(uv, pv, cupp);
                ST[cl]      = fmaf(a, st0, vc.x * uv);     // old st used above only
                ST[16 + cl] = fmaf(a, st1, vc.y * uv);
            }
            w0 = red8(w0); w1 = red8(w1); h0 = red8(h0); h1 = red8(h1);
            const float cu  = red8(cuup);
            const float cup = red8(cupp);
            n2 = a2v * n2 + 2.0f * a * cup + cu * cv;      // ||S_t||_F^2 recurrence
            if (j == 0) {
                *(float2*)&wsv[r0] = make_float2(w0, w1);
                *(float2*)&hs[r0]  = make_float2(h0, h1);
            }
            // commit next-chunk staging to the other LDS buffer
            if (doPre) {
                float* kn = kc[cb ^ 1]; float* qn = qc[cb ^ 1]; float* xn = xc[cb ^ 1];
                {
                    int seg = w * 3 + 0, arr = seg >> 3, sub = seg & 7;
                    *(float4*)((arr == 0 ? kn : (arr == 1 ? qn : xn))
                               + sub * 256 + lane * 4) = pre0;
                }
                {
                    int seg = w * 3 + 1, arr = seg >> 3, sub = seg & 7;
                    *(float4*)((arr == 0 ? kn : (arr == 1 ? qn : xn))
                               + sub * 256 + lane * 4) = pre1;
                }
                {
                    int seg = w * 3 + 2, arr = seg >> 3, sub = seg & 7;
                    *(float4*)((arr == 0 ? kn : (arr == 1 ? qn : xn))
                               + sub * 256 + lane * 4) = pre2;
                }
            }
            __syncthreads();                               // barrier 2 (LDS only*)

            // ---- phase 6 (row side): g = S w; rank-3 A; S, M updates; y = M q ----
            float ww[16], hh[16], qq[16];
            {
                const float4* w4 = (const float4*)wsv;
                const float4* h4 = (const float4*)hs;
                const float4* q4 = (const float4*)(qcb + so);
                #pragma unroll
                for (int m = 0; m < 4; ++m) {
                    float4 a4 = w4[j + 8 * m], b4 = h4[j + 8 * m], c4v = q4[j + 8 * m];
                    ww[4*m+0] = a4.x;  ww[4*m+1] = a4.y;
                    ww[4*m+2] = a4.z;  ww[4*m+3] = a4.w;
                    hh[4*m+0] = b4.x;  hh[4*m+1] = b4.y;
                    hh[4*m+2] = b4.z;  hh[4*m+3] = b4.w;
                    qq[4*m+0] = c4v.x; qq[4*m+1] = c4v.y;
                    qq[4*m+2] = c4v.z; qq[4*m+3] = c4v.w;
                }
            }
            float g0 = 0.f, g1 = 0.f;
            #pragma unroll
            for (int cl = 0; cl < 16; ++cl) {
                g0 = fmaf(S[cl],      ww[cl], g0);
                g1 = fmaf(S[16 + cl], ww[cl], g1);
            }
            g0 = red8(g0); g1 = red8(g1);

            const float rho0 = a2v * g0 + a * cu * p0 + (a * cup + cv * cu) * u0;
            const float rho1 = a2v * g1 + a * cu * p1 + (a * cup + cv * cu) * u1;
            const float sg0  = a2v * p0 + a * cv * u0;
            const float sg1  = a2v * p1 + a * cv * u1;
            const float ta0  = a2v * u0, ta1 = a2v * u1;
            const float nrm  = sqrtf(fmaxf(n2, 0.f)) + 1e-6f;
            const float rn   = 1.0f / nrm;
            const float c1   = -0.015f * rn;    // 0.99M - 0.01*(1.5 S/n - 0.5 A/n^3)
            const float c2   = 0.005f * rn * rn * rn;

            float y0 = 0.f, y1 = 0.f;
            #pragma unroll
            for (int cl = 0; cl < 16; ++cl) {
                float kv = kk[cl], wv = ww[cl], hv = hh[cl], qv = qq[cl];
                S[cl]      = fmaf(a, S[cl],      u0 * kv);
                S[16 + cl] = fmaf(a, S[16 + cl], u1 * kv);
                A[cl]      = fmaf(a3v, A[cl],
                                  fmaf(rho0, kv, fmaf(sg0, wv, ta0 * hv)));
                A[16 + cl] = fmaf(a3v, A[16 + cl],
                                  fmaf(rho1, kv, fmaf(sg1, wv, ta1 * hv)));
                M[cl]      = fmaf(0.99f, M[cl],      fmaf(c1, S[cl],      c2 * A[cl]));
                M[16 + cl] = fmaf(0.99f, M[16 + cl], fmaf(c1, S[16 + cl], c2 * A[16 + cl]));
                y0 = fmaf(M[cl],      qv, y0);
                y1 = fmaf(M[16 + cl], qv, y1);
            }
            y0 = red8(y0); y1 = red8(y1);
            if (j == 0)
                *(float2*)&yc[so + r0] = make_float2(y0, y1);
        }

        // chunk end: flush yc -> ys (one float4 per thread)
        __syncthreads();
        float4 yv = *(float4*)&yc[tid * 4];
        *(float4*)(ys + base + (size_t)tc * CH * DD + tid * 4) = yv;
    }
}

// ---------------- epilogue: out = ys @ Wout^T + bout ---------------------------
__global__ __launch_bounds__(128) void epilogue_kernel(
        const float* __restrict__ ys, const float* __restrict__ WoutT,
        const float* __restrict__ bout, float* __restrict__ out) {
    const int row0 = blockIdx.x * 4;
    const int e = threadIdx.x;
    __shared__ float yr[4][DD];
    #pragma unroll
    for (int rr = 0; rr < 4; ++rr)
        yr[rr][e] = ys[(size_t)(row0 + rr) * DD + e];
    __syncthreads();
    float acc[4] = {0,0,0,0};
    #pragma unroll 4
    for (int d = 0; d < DD; ++d) {
        float w = WoutT[d * DD + e];
        #pragma unroll
        for (int rr = 0; rr < 4; ++rr) acc[rr] = fmaf(yr[rr][d], w, acc[rr]);
    }
    const float bo = bout[e];
    #pragma unroll
    for (int rr = 0; rr < 4; ++rr)
        out[(size_t)(row0 + rr) * DD + e] = acc[rr] + bo;
}

extern "C" void kernel_launch(void* const* d_in, const int* in_sizes, int n_in,
                              void* d_out, int out_size, void* d_ws, size_t ws_size,
                              hipStream_t stream) {
    const float* x        = (const float*)d_in[0];
    const float* Wq       = (const float*)d_in[1];
    const float* Wk       = (const float*)d_in[2];
    const float* P0       = (const float*)d_in[3];
    const float* M0       = (const float*)d_in[4];
    const float* S0       = (const float*)d_in[5];
    const float* log_gain = (const float*)d_in[6];
    const float* coeffs   = (const float*)d_in[7];
    const float* Wout     = (const float*)d_in[8];
    const float* bout     = (const float*)d_in[9];
    float* out = (float*)d_out;

    float* ws    = (float*)d_ws;
    float* WqT   = ws;                      // 16384
    float* WkT   = ws + 16384;              // 16384
    float* WoutT = ws + 32768;              // 16384
    float* kphi  = ws + 49152;              // B*L*D each below
    float* qphi  = kphi + (size_t)BB * LL * DD;
    float* ysb   = qphi + (size_t)BB * LL * DD;

    hipLaunchKernelGGL(transpose3_kernel, dim3(3), dim3(256), 0, stream,
                       Wq, Wk, Wout, WqT, WkT, WoutT);
    hipLaunchKernelGGL(prologue_kernel, dim3(BB * LL / 4), dim3(128), 0, stream,
                       x, WqT, WkT, P0, log_gain, coeffs, kphi, qphi);
    hipLaunchKernelGGL(scan_kernel, dim3(BB), dim3(512), 0, stream,
                       kphi, qphi, x, M0, S0, ysb);
    hipLaunchKernelGGL(epilogue_kernel, dim3(BB * LL / 4), dim3(128), 0, stream,
                       ysb, WoutT, bout, out);
}

// Round 14
// 2035.416 us; speedup vs baseline: 1.7686x; 1.0015x over previous
//
#include <hip/hip_runtime.h>

#define BB 16
#define LL 512
#define DD 128
#define CH 16
#define NCH (LL / CH)

// 8-lane all-reduce sum (lanes within a DPP half-row), pure VALU:
// quad xor1, quad xor2, then half-row mirror pairs the two quads.
__device__ __forceinline__ float red8(float v) {
    v += __int_as_float(__builtin_amdgcn_update_dpp(
            0, __float_as_int(v), 0xB1, 0xF, 0xF, true));
    v += __int_as_float(__builtin_amdgcn_update_dpp(
            0, __float_as_int(v), 0x4E, 0xF, 0xF, true));
    v += __int_as_float(__builtin_amdgcn_update_dpp(
            0, __float_as_int(v), 0x141, 0xF, 0xF, true));
    return v;
}

#define SCAN_REGS __attribute__((amdgpu_waves_per_eu(2, 2)))

// ---------------- transpose Wq, Wk, Wout (once per call, tiny) ----------------
__global__ void transpose3_kernel(const float* __restrict__ Wq,
                                  const float* __restrict__ Wk,
                                  const float* __restrict__ Wout,
                                  float* __restrict__ WqT,
                                  float* __restrict__ WkT,
                                  float* __restrict__ WoutT) {
    const float* src; float* dst;
    if (blockIdx.x == 0)      { src = Wq;   dst = WqT;   }
    else if (blockIdx.x == 1) { src = Wk;   dst = WkT;   }
    else                      { src = Wout; dst = WoutT; }
    for (int idx = threadIdx.x; idx < DD * DD; idx += blockDim.x) {
        int r = idx >> 7, c = idx & 127;
        dst[c * DD + r] = src[idx];
    }
}

// ---------------- prologue: q/k projections, k-normalize, P0 rotation, poly ----
// 8 rows per block (vs 4): the d-loop does 2 weight loads per 16 FMAs instead
// of per 8, and total weight re-streaming halves. Accumulation/reduction order
// per output is unchanged -> bit-identical results to the 4-row version.
__global__ __launch_bounds__(128) void prologue_kernel(
        const float* __restrict__ x, const float* __restrict__ WqT,
        const float* __restrict__ WkT, const float* __restrict__ P0,
        const float* __restrict__ log_gain, const float* __restrict__ coeffs,
        float* __restrict__ kphi, float* __restrict__ qphi) {
    const int row0 = blockIdx.x * 8;
    const int e = threadIdx.x;
    __shared__ float xs[8][DD];
    __shared__ float qrow[8][DD];
    __shared__ float wred[8][2];

    #pragma unroll
    for (int rr = 0; rr < 8; ++rr)
        xs[rr][e] = x[(size_t)(row0 + rr) * DD + e];
    __syncthreads();

    float aq[8] = {0,0,0,0,0,0,0,0}, ak[8] = {0,0,0,0,0,0,0,0};
    #pragma unroll 4
    for (int d = 0; d < DD; ++d) {
        float wq = WqT[d * DD + e];
        float wk = WkT[d * DD + e];
        #pragma unroll
        for (int rr = 0; rr < 8; ++rr) {
            float xv = xs[rr][d];
            aq[rr] = fmaf(xv, wq, aq[rr]);
            ak[rr] = fmaf(xv, wk, ak[rr]);
        }
    }
    const int lane = threadIdx.x & 63, wv = threadIdx.x >> 6;
    #pragma unroll
    for (int rr = 0; rr < 8; ++rr) {
        float s = ak[rr] * ak[rr];
        #pragma unroll
        for (int m = 1; m <= 32; m <<= 1) s += __shfl_xor(s, m);
        if (lane == 0) wred[rr][wv] = s;
    }
    __syncthreads();
    const float c0 = coeffs[0], c1v = coeffs[1];
    #pragma unroll
    for (int rr = 0; rr < 8; ++rr) {
        float s = wred[rr][0] + wred[rr][1];
        float kn = ak[rr] / fmaxf(sqrtf(s), 1e-12f);
        kphi[(size_t)(row0 + rr) * DD + e] = c0 * kn + c1v * kn * kn;
        qrow[rr][e] = aq[rr];
    }
    __syncthreads();
    float acc[8] = {0,0,0,0,0,0,0,0};
    #pragma unroll 4
    for (int d = 0; d < DD; ++d) {
        float pv = P0[d * DD + e];
        #pragma unroll
        for (int rr = 0; rr < 8; ++rr) acc[rr] = fmaf(qrow[rr][d], pv, acc[rr]);
    }
    const float g = expf(log_gain[e]);
    #pragma unroll
    for (int rr = 0; rr < 8; ++rr) {
        float qa = tanhf(g * acc[rr]);
        qphi[(size_t)(row0 + rr) * DD + e] = c0 * qa + c1v * qa * qa;
    }
}

// ---------------- main sequential scan: one block per batch --------------------
// R8 CHAMPION, verbatim (re-validated R13: 1,915 us scan). 512 threads,
// chunked LDS staging: k/q/x bulk-copied into LDS in 16-step double-buffered
// chunks; ys buffered in LDS and flushed once per chunk -> steady-state
// per-step barriers have NO outstanding vmem, so the compiler's mandatory
// `s_waitcnt vmcnt(0)` before each s_barrier is free. Thread (g = tid>>3,
// j = tid&7): rows {2g,2g+1}; interleaved column set col(m,l) = 4j + 32m + l
// (float4s {j+8m}) -> unpadded LDS vector reads are conflict-free. ST holds
// the transpose tile for the same index partition. 8-lane DPP butterflies for
// all reductions. A = S S^T S via exact rank-3 recurrence; ||S||_F^2 via
// scalar recurrence.
// DO NOT raise peak liveness: this kernel sits at the 128-arch-VGPR edge.
// R9 (reg prefetch), R10 (split accumulators), R12 (held float4s/CSEL) each
// regressed 19-80% by adding/rigidifying live ranges. Allocator knobs
// (launch_bounds, waves_per_eu, agpr_alloc, LDS forcing) never move VGPR off
// 128 — tested R5/R6/R7/R9/R11.
__global__ SCAN_REGS __launch_bounds__(512)
void scan_kernel(
        const float* __restrict__ kphi, const float* __restrict__ qphi,
        const float* __restrict__ x, const float* __restrict__ M0,
        const float* __restrict__ S0, float* __restrict__ ys) {
    const int b    = blockIdx.x;
    const int tid  = threadIdx.x;
    const int j    = tid & 7;
    const int g    = tid >> 3;
    const int r0   = 2 * g;
    const int w    = tid >> 6;
    const int lane = tid & 63;

    __shared__ __align__(16) float kc[2][CH * DD];
    __shared__ __align__(16) float qc[2][CH * DD];
    __shared__ __align__(16) float xc[2][CH * DD];
    __shared__ __align__(16) float yc[CH * DD];
    __shared__ __align__(16) float us[DD], ps[DD], wsv[DD], hs[DD];
    __shared__ float red[64];
    __shared__ float n2sh;

    float S[32], ST[32], A[32], M[32];
    {
        const float4* S04 = (const float4*)S0;
        const float4* M04 = (const float4*)M0;
        #pragma unroll
        for (int rl = 0; rl < 2; ++rl)
            #pragma unroll
            for (int m = 0; m < 4; ++m) {
                int f4 = (r0 + rl) * 32 + j + 8 * m;
                float4 s4 = S04[f4], m4 = M04[f4];
                int i = rl * 16 + 4 * m;
                S[i+0] = s4.x; S[i+1] = s4.y; S[i+2] = s4.z; S[i+3] = s4.w;
                M[i+0] = m4.x; M[i+1] = m4.y; M[i+2] = m4.z; M[i+3] = m4.w;
            }
        #pragma unroll
        for (int rl = 0; rl < 2; ++rl)
            #pragma unroll
            for (int m = 0; m < 4; ++m)
                #pragma unroll
                for (int l = 0; l < 4; ++l)
                    ST[rl*16 + 4*m + l] =
                        S0[(size_t)(4*j + 32*m + l) * DD + r0 + rl];
        #pragma unroll
        for (int i = 0; i < 32; ++i) A[i] = 0.f;   // exact when S0 == 0
    }

    // ||S0||^2 block reduction
    float sp = 0.f;
    #pragma unroll
    for (int i = 0; i < 32; ++i) sp = fmaf(S[i], S[i], sp);
    sp = red8(sp);
    if (j == 0) red[g] = sp;

    const size_t base = (size_t)b * LL * DD;

    // preload chunk 0 (each wave copies 3 x 1KB segments)
    #pragma unroll
    for (int i = 0; i < 3; ++i) {
        int seg = w * 3 + i, arr = seg >> 3, sub = seg & 7;
        const float* sp0 = (arr == 0 ? kphi : (arr == 1 ? qphi : x))
                           + base + sub * 256 + lane * 4;
        float* dp = (arr == 0 ? kc[0] : (arr == 1 ? qc[0] : xc[0]))
                    + sub * 256 + lane * 4;
        *(float4*)dp = *(const float4*)sp0;
    }
    __syncthreads();
    if (tid < 64) {
        float s = red[tid];
        #pragma unroll
        for (int m = 1; m <= 32; m <<= 1) s += __shfl_xor(s, m);
        if (tid == 0) n2sh = s;
    }
    __syncthreads();
    float n2 = n2sh;

    const float a = 0.9f, a2v = 0.81f, a3v = 0.729f;

    #pragma unroll 1
    for (int tc = 0; tc < NCH; ++tc) {
        const int cb = tc & 1;
        const float* kcb = kc[cb];
        const float* qcb = qc[cb];
        const float* xcb = xc[cb];

        #pragma unroll 1
        for (int sl = 0; sl < CH; ++sl) {
            const int so = sl * DD;

            // issue next-chunk staging loads at chunk start (drained ~1x/chunk)
            float4 pre0, pre1, pre2;
            const bool doPre = (sl == 0) && (tc + 1 < NCH);
            if (doPre) {
                const size_t nbg = base + (size_t)(tc + 1) * CH * DD;
                {
                    int seg = w * 3 + 0, arr = seg >> 3, sub = seg & 7;
                    pre0 = *(const float4*)((arr == 0 ? kphi : (arr == 1 ? qphi : x))
                                            + nbg + sub * 256 + lane * 4);
                }
                {
                    int seg = w * 3 + 1, arr = seg >> 3, sub = seg & 7;
                    pre1 = *(const float4*)((arr == 0 ? kphi : (arr == 1 ? qphi : x))
                                            + nbg + sub * 256 + lane * 4);
                }
                {
                    int seg = w * 3 + 2, arr = seg >> 3, sub = seg & 7;
                    pre2 = *(const float4*)((arr == 0 ? kphi : (arr == 1 ? qphi : x))
                                            + nbg + sub * 256 + lane * 4);
                }
            }

            // ---- phase 2 (row side): pred = M k, p = S v, cv = v.v ----
            float kk[16];
            {
                const float4* k4 = (const float4*)(kcb + so);
                #pragma unroll
                for (int m = 0; m < 4; ++m) {
                    float4 v4 = k4[j + 8 * m];
                    kk[4*m+0] = v4.x; kk[4*m+1] = v4.y;
                    kk[4*m+2] = v4.z; kk[4*m+3] = v4.w;
                }
            }
            float pr0 = 0.f, pr1 = 0.f, pp0 = 0.f, pp1 = 0.f, cvp = 0.f;
            #pragma unroll
            for (int cl = 0; cl < 16; ++cl) {
                float kv = kk[cl];
                pr0 = fmaf(M[cl],      kv, pr0);
                pr1 = fmaf(M[16 + cl], kv, pr1);
                pp0 = fmaf(S[cl],      kv, pp0);
                pp1 = fmaf(S[16 + cl], kv, pp1);
                cvp = fmaf(kv, kv, cvp);
            }
            pr0 = red8(pr0); pr1 = red8(pr1);
            pp0 = red8(pp0); pp1 = red8(pp1);
            const float cv = red8(cvp);
            const float2 xv = *(const float2*)&xcb[so + r0];
            const float u0 = pr0 - xv.x, u1 = pr1 - xv.y;
            const float p0 = pp0, p1 = pp1;
            if (j == 0) {
                *(float2*)&us[r0] = make_float2(u0, u1);
                *(float2*)&ps[r0] = make_float2(p0, p1);
            }
            __syncthreads();                               // barrier 1 (LDS only)

            // ---- phase 4 (col side): w = S^T u, h = S^T p, dots; ST update ----
            float uu[16], pa[16];
            {
                const float4* u4 = (const float4*)us;
                const float4* p4 = (const float4*)ps;
                #pragma unroll
                for (int m = 0; m < 4; ++m) {
                    float4 a4 = u4[j + 8 * m], b4 = p4[j + 8 * m];
                    uu[4*m+0] = a4.x; uu[4*m+1] = a4.y;
                    uu[4*m+2] = a4.z; uu[4*m+3] = a4.w;
                    pa[4*m+0] = b4.x; pa[4*m+1] = b4.y;
                    pa[4*m+2] = b4.z; pa[4*m+3] = b4.w;
                }
            }
            const float2 vc = *(const float2*)&kcb[so + r0];
            float w0 = 0.f, w1 = 0.f, h0 = 0.f, h1 = 0.f, cuup = 0.f, cupp = 0.f;
            #pragma unroll
            for (int cl = 0; cl < 16; ++cl) {
                float uv = uu[cl], pv = pa[cl];
                float st0 = ST[cl], st1 = ST[16 + cl];
                w0 = fmaf(st0, uv, w0);  w1 = fmaf(st1, uv, w1);
                h0 = fmaf(st0, pv, h0);  h1 = fmaf(st1, pv, h1);
                cuup = fmaf(uv, uv, cuup);
                cupp = fmaf(uv, pv, cupp);
                ST[cl]      = fmaf(a, st0, vc.x * uv);     // old st used above only
                ST[16 + cl] = fmaf(a, st1, vc.y * uv);
            }
            w0 = red8(w0); w1 = red8(w1); h0 = red8(h0); h1 = red8(h1);
            const float cu  = red8(cuup);
            const float cup = red8(cupp);
            n2 = a2v * n2 + 2.0f * a * cup + cu * cv;      // ||S_t||_F^2 recurrence
            if (j == 0) {
                *(float2*)&wsv[r0] = make_float2(w0, w1);
                *(float2*)&hs[r0]  = make_float2(h0, h1);
            }
            // commit next-chunk staging to the other LDS buffer
            if (doPre) {
                float* kn = kc[cb ^ 1]; float* qn = qc[cb ^ 1]; float* xn = xc[cb ^ 1];
                {
                    int seg = w * 3 + 0, arr = seg >> 3, sub = seg & 7;
                    *(float4*)((arr == 0 ? kn : (arr == 1 ? qn : xn))
                               + sub * 256 + lane * 4) = pre0;
                }
                {
                    int seg = w * 3 + 1, arr = seg >> 3, sub = seg & 7;
                    *(float4*)((arr == 0 ? kn : (arr == 1 ? qn : xn))
                               + sub * 256 + lane * 4) = pre1;
                }
                {
                    int seg = w * 3 + 2, arr = seg >> 3, sub = seg & 7;
                    *(float4*)((arr == 0 ? kn : (arr == 1 ? qn : xn))
                               + sub * 256 + lane * 4) = pre2;
                }
            }
            __syncthreads();                               // barrier 2 (LDS only*)

            // ---- phase 6 (row side): g = S w; rank-3 A; S, M updates; y = M q ----
            float ww[16], hh[16], qq[16];
            {
                const float4* w4 = (const float4*)wsv;
                const float4* h4 = (const float4*)hs;
                const float4* q4 = (const float4*)(qcb + so);
                #pragma unroll
                for (int m = 0; m < 4; ++m) {
                    float4 a4 = w4[j + 8 * m], b4 = h4[j + 8 * m], c4v = q4[j + 8 * m];
                    ww[4*m+0] = a4.x;  ww[4*m+1] = a4.y;
                    ww[4*m+2] = a4.z;  ww[4*m+3] = a4.w;
                    hh[4*m+0] = b4.x;  hh[4*m+1] = b4.y;
                    hh[4*m+2] = b4.z;  hh[4*m+3] = b4.w;
                    qq[4*m+0] = c4v.x; qq[4*m+1] = c4v.y;
                    qq[4*m+2] = c4v.z; qq[4*m+3] = c4v.w;
                }
            }
            float g0 = 0.f, g1 = 0.f;
            #pragma unroll
            for (int cl = 0; cl < 16; ++cl) {
                g0 = fmaf(S[cl],      ww[cl], g0);
                g1 = fmaf(S[16 + cl], ww[cl], g1);
            }
            g0 = red8(g0); g1 = red8(g1);

            const float rho0 = a2v * g0 + a * cu * p0 + (a * cup + cv * cu) * u0;
            const float rho1 = a2v * g1 + a * cu * p1 + (a * cup + cv * cu) * u1;
            const float sg0  = a2v * p0 + a * cv * u0;
            const float sg1  = a2v * p1 + a * cv * u1;
            const float ta0  = a2v * u0, ta1 = a2v * u1;
            const float nrm  = sqrtf(fmaxf(n2, 0.f)) + 1e-6f;
            const float rn   = 1.0f / nrm;
            const float c1   = -0.015f * rn;    // 0.99M - 0.01*(1.5 S/n - 0.5 A/n^3)
            const float c2   = 0.005f * rn * rn * rn;

            float y0 = 0.f, y1 = 0.f;
            #pragma unroll
            for (int cl = 0; cl < 16; ++cl) {
                float kv = kk[cl], wv = ww[cl], hv = hh[cl], qv = qq[cl];
                S[cl]      = fmaf(a, S[cl],      u0 * kv);
                S[16 + cl] = fmaf(a, S[16 + cl], u1 * kv);
                A[cl]      = fmaf(a3v, A[cl],
                                  fmaf(rho0, kv, fmaf(sg0, wv, ta0 * hv)));
                A[16 + cl] = fmaf(a3v, A[16 + cl],
                                  fmaf(rho1, kv, fmaf(sg1, wv, ta1 * hv)));
                M[cl]      = fmaf(0.99f, M[cl],      fmaf(c1, S[cl],      c2 * A[cl]));
                M[16 + cl] = fmaf(0.99f, M[16 + cl], fmaf(c1, S[16 + cl], c2 * A[16 + cl]));
                y0 = fmaf(M[cl],      qv, y0);
                y1 = fmaf(M[16 + cl], qv, y1);
            }
            y0 = red8(y0); y1 = red8(y1);
            if (j == 0)
                *(float2*)&yc[so + r0] = make_float2(y0, y1);
        }

        // chunk end: flush yc -> ys (one float4 per thread)
        __syncthreads();
        float4 yv = *(float4*)&yc[tid * 4];
        *(float4*)(ys + base + (size_t)tc * CH * DD + tid * 4) = yv;
    }
}

// ---------------- epilogue: out = ys @ Wout^T + bout ---------------------------
// 8 rows per block: 1 weight load per 8 FMAs (vs 4), halved weight re-stream.
__global__ __launch_bounds__(128) void epilogue_kernel(
        const float* __restrict__ ys, const float* __restrict__ WoutT,
        const float* __restrict__ bout, float* __restrict__ out) {
    const int row0 = blockIdx.x * 8;
    const int e = threadIdx.x;
    __shared__ float yr[8][DD];
    #pragma unroll
    for (int rr = 0; rr < 8; ++rr)
        yr[rr][e] = ys[(size_t)(row0 + rr) * DD + e];
    __syncthreads();
    float acc[8] = {0,0,0,0,0,0,0,0};
    #pragma unroll 4
    for (int d = 0; d < DD; ++d) {
        float w = WoutT[d * DD + e];
        #pragma unroll
        for (int rr = 0; rr < 8; ++rr) acc[rr] = fmaf(yr[rr][d], w, acc[rr]);
    }
    const float bo = bout[e];
    #pragma unroll
    for (int rr = 0; rr < 8; ++rr)
        out[(size_t)(row0 + rr) * DD + e] = acc[rr] + bo;
}

extern "C" void kernel_launch(void* const* d_in, const int* in_sizes, int n_in,
                              void* d_out, int out_size, void* d_ws, size_t ws_size,
                              hipStream_t stream) {
    const float* x        = (const float*)d_in[0];
    const float* Wq       = (const float*)d_in[1];
    const float* Wk       = (const float*)d_in[2];
    const float* P0       = (const float*)d_in[3];
    const float* M0       = (const float*)d_in[4];
    const float* S0       = (const float*)d_in[5];
    const float* log_gain = (const float*)d_in[6];
    const float* coeffs   = (const float*)d_in[7];
    const float* Wout     = (const float*)d_in[8];
    const float* bout     = (const float*)d_in[9];
    float* out = (float*)d_out;

    float* ws    = (float*)d_ws;
    float* WqT   = ws;                      // 16384
    float* WkT   = ws + 16384;              // 16384
    float* WoutT = ws + 32768;              // 16384
    float* kphi  = ws + 49152;              // B*L*D each below
    float* qphi  = kphi + (size_t)BB * LL * DD;
    float* ysb   = qphi + (size_t)BB * LL * DD;

    hipLaunchKernelGGL(transpose3_kernel, dim3(3), dim3(256), 0, stream,
                       Wq, Wk, Wout, WqT, WkT, WoutT);
    hipLaunchKernelGGL(prologue_kernel, dim3(BB * LL / 8), dim3(128), 0, stream,
                       x, WqT, WkT, P0, log_gain, coeffs, kphi, qphi);
    hipLaunchKernelGGL(scan_kernel, dim3(BB), dim3(512), 0, stream,
                       kphi, qphi, x, M0, S0, ysb);
    hipLaunchKernelGGL(epilogue_kernel, dim3(BB * LL / 8), dim3(128), 0, stream,
                       ysb, WoutT, bout, out);
}

// Round 15
// 1506.349 us; speedup vs baseline: 2.3897x; 1.3512x over previous
//
#include <hip/hip_runtime.h>

#define BB 16
#define LL 512
#define DD 128
#define CH 16
#define NCH (LL / CH)

typedef float v2f __attribute__((ext_vector_type(2)));
__device__ __forceinline__ v2f mk2(float x, float y) { v2f r; r.x = x; r.y = y; return r; }
__device__ __forceinline__ v2f fma2(v2f a, v2f b, v2f c) {
    return __builtin_elementwise_fma(a, b, c);   // v_pk_fma_f32
}

// 8-lane all-reduce sum (lanes within a DPP half-row), pure VALU:
// quad xor1, quad xor2, then half-row mirror pairs the two quads.
__device__ __forceinline__ float red8(float v) {
    v += __int_as_float(__builtin_amdgcn_update_dpp(
            0, __float_as_int(v), 0xB1, 0xF, 0xF, true));
    v += __int_as_float(__builtin_amdgcn_update_dpp(
            0, __float_as_int(v), 0x4E, 0xF, 0xF, true));
    v += __int_as_float(__builtin_amdgcn_update_dpp(
            0, __float_as_int(v), 0x141, 0xF, 0xF, true));
    return v;
}

#define SCAN_REGS __attribute__((amdgpu_waves_per_eu(2, 2)))

// ---------------- transpose Wq, Wk, Wout (once per call, tiny) ----------------
__global__ void transpose3_kernel(const float* __restrict__ Wq,
                                  const float* __restrict__ Wk,
                                  const float* __restrict__ Wout,
                                  float* __restrict__ WqT,
                                  float* __restrict__ WkT,
                                  float* __restrict__ WoutT) {
    const float* src; float* dst;
    if (blockIdx.x == 0)      { src = Wq;   dst = WqT;   }
    else if (blockIdx.x == 1) { src = Wk;   dst = WkT;   }
    else                      { src = Wout; dst = WoutT; }
    for (int idx = threadIdx.x; idx < DD * DD; idx += blockDim.x) {
        int r = idx >> 7, c = idx & 127;
        dst[c * DD + r] = src[idx];
    }
}

// ---------------- prologue: q/k projections, k-normalize, P0 rotation, poly ----
__global__ __launch_bounds__(128) void prologue_kernel(
        const float* __restrict__ x, const float* __restrict__ WqT,
        const float* __restrict__ WkT, const float* __restrict__ P0,
        const float* __restrict__ log_gain, const float* __restrict__ coeffs,
        float* __restrict__ kphi, float* __restrict__ qphi) {
    const int row0 = blockIdx.x * 8;
    const int e = threadIdx.x;
    __shared__ float xs[8][DD];
    __shared__ float qrow[8][DD];
    __shared__ float wred[8][2];

    #pragma unroll
    for (int rr = 0; rr < 8; ++rr)
        xs[rr][e] = x[(size_t)(row0 + rr) * DD + e];
    __syncthreads();

    float aq[8] = {0,0,0,0,0,0,0,0}, ak[8] = {0,0,0,0,0,0,0,0};
    #pragma unroll 4
    for (int d = 0; d < DD; ++d) {
        float wq = WqT[d * DD + e];
        float wk = WkT[d * DD + e];
        #pragma unroll
        for (int rr = 0; rr < 8; ++rr) {
            float xv = xs[rr][d];
            aq[rr] = fmaf(xv, wq, aq[rr]);
            ak[rr] = fmaf(xv, wk, ak[rr]);
        }
    }
    const int lane = threadIdx.x & 63, wv = threadIdx.x >> 6;
    #pragma unroll
    for (int rr = 0; rr < 8; ++rr) {
        float s = ak[rr] * ak[rr];
        #pragma unroll
        for (int m = 1; m <= 32; m <<= 1) s += __shfl_xor(s, m);
        if (lane == 0) wred[rr][wv] = s;
    }
    __syncthreads();
    const float c0 = coeffs[0], c1v = coeffs[1];
    #pragma unroll
    for (int rr = 0; rr < 8; ++rr) {
        float s = wred[rr][0] + wred[rr][1];
        float kn = ak[rr] / fmaxf(sqrtf(s), 1e-12f);
        kphi[(size_t)(row0 + rr) * DD + e] = c0 * kn + c1v * kn * kn;
        qrow[rr][e] = aq[rr];
    }
    __syncthreads();
    float acc[8] = {0,0,0,0,0,0,0,0};
    #pragma unroll 4
    for (int d = 0; d < DD; ++d) {
        float pv = P0[d * DD + e];
        #pragma unroll
        for (int rr = 0; rr < 8; ++rr) acc[rr] = fmaf(qrow[rr][d], pv, acc[rr]);
    }
    const float g = expf(log_gain[e]);
    #pragma unroll
    for (int rr = 0; rr < 8; ++rr) {
        float qa = tanhf(g * acc[rr]);
        qphi[(size_t)(row0 + rr) * DD + e] = c0 * qa + c1v * qa * qa;
    }
}

// ---------------- main sequential scan: one block per batch --------------------
// R8 champion structure (chunked LDS staging, vmem-free per-step barriers,
// single-accumulator reductions) with ONE change: all elementwise state
// updates (ST/S/A/M, ~352 scalar instr/thread/step) are packed into v2f
// column-pairs -> v_pk_fma_f32/v_pk_mul_f32 halve their issue count.
// Per-element rounding and order are IDENTICAL to the scalar version (packed
// mul and fma round each lane exactly as fmaf(a,s,b*c) did) -> bit-identical
// output. Reductions stay scalar single-accumulator (R10: split accumulators
// regress). Thread (g = tid>>3, j = tid&7): rows {2g,2g+1}; interleaved
// column set col(m,l) = 4j + 32m + l -> conflict-free unpadded vector reads.
// A = S S^T S via exact rank-3 recurrence; ||S||_F^2 via scalar recurrence.
// DO NOT raise peak liveness beyond this: the kernel sits at the 128-arch-
// VGPR edge (R9/R10/R12 regressions; allocator knobs immovable R5-R11).
__global__ SCAN_REGS __launch_bounds__(512)
void scan_kernel(
        const float* __restrict__ kphi, const float* __restrict__ qphi,
        const float* __restrict__ x, const float* __restrict__ M0,
        const float* __restrict__ S0, float* __restrict__ ys) {
    const int b    = blockIdx.x;
    const int tid  = threadIdx.x;
    const int j    = tid & 7;
    const int g    = tid >> 3;
    const int r0   = 2 * g;
    const int w    = tid >> 6;
    const int lane = tid & 63;

    __shared__ __align__(16) float kc[2][CH * DD];
    __shared__ __align__(16) float qc[2][CH * DD];
    __shared__ __align__(16) float xc[2][CH * DD];
    __shared__ __align__(16) float yc[CH * DD];
    __shared__ __align__(16) float us[DD], ps[DD], wsv[DD], hs[DD];
    __shared__ float red[64];
    __shared__ float n2sh;

    // state as column-pairs: index p<8 = row r0, p in [8,16) = row r0+1
    v2f S2[16], ST2[16], A2[16], M2[16];
    {
        const float4* S04 = (const float4*)S0;
        const float4* M04 = (const float4*)M0;
        #pragma unroll
        for (int rl = 0; rl < 2; ++rl)
            #pragma unroll
            for (int m = 0; m < 4; ++m) {
                int f4 = (r0 + rl) * 32 + j + 8 * m;
                float4 s4 = S04[f4], m4 = M04[f4];
                int p = rl * 8 + 2 * m;
                S2[p]     = mk2(s4.x, s4.y);
                S2[p + 1] = mk2(s4.z, s4.w);
                M2[p]     = mk2(m4.x, m4.y);
                M2[p + 1] = mk2(m4.z, m4.w);
            }
        #pragma unroll
        for (int rl = 0; rl < 2; ++rl)
            #pragma unroll
            for (int m = 0; m < 4; ++m) {
                int p = rl * 8 + 2 * m;
                ST2[p]     = mk2(S0[(size_t)(4*j + 32*m + 0) * DD + r0 + rl],
                                 S0[(size_t)(4*j + 32*m + 1) * DD + r0 + rl]);
                ST2[p + 1] = mk2(S0[(size_t)(4*j + 32*m + 2) * DD + r0 + rl],
                                 S0[(size_t)(4*j + 32*m + 3) * DD + r0 + rl]);
            }
        #pragma unroll
        for (int p = 0; p < 16; ++p) A2[p] = mk2(0.f, 0.f);  // exact: S0 == 0
    }

    // ||S0||^2 block reduction
    float sp = 0.f;
    #pragma unroll
    for (int p = 0; p < 16; ++p) {
        sp = fmaf(S2[p].x, S2[p].x, sp);
        sp = fmaf(S2[p].y, S2[p].y, sp);
    }
    sp = red8(sp);
    if (j == 0) red[g] = sp;

    const size_t base = (size_t)b * LL * DD;

    // preload chunk 0 (each wave copies 3 x 1KB segments)
    #pragma unroll
    for (int i = 0; i < 3; ++i) {
        int seg = w * 3 + i, arr = seg >> 3, sub = seg & 7;
        const float* sp0 = (arr == 0 ? kphi : (arr == 1 ? qphi : x))
                           + base + sub * 256 + lane * 4;
        float* dp = (arr == 0 ? kc[0] : (arr == 1 ? qc[0] : xc[0]))
                    + sub * 256 + lane * 4;
        *(float4*)dp = *(const float4*)sp0;
    }
    __syncthreads();
    if (tid < 64) {
        float s = red[tid];
        #pragma unroll
        for (int m = 1; m <= 32; m <<= 1) s += __shfl_xor(s, m);
        if (tid == 0) n2sh = s;
    }
    __syncthreads();
    float n2 = n2sh;

    const float a = 0.9f, a2v = 0.81f, a3v = 0.729f;
    const v2f av = mk2(a, a);

    #pragma unroll 1
    for (int tc = 0; tc < NCH; ++tc) {
        const int cb = tc & 1;
        const float* kcb = kc[cb];
        const float* qcb = qc[cb];
        const float* xcb = xc[cb];

        #pragma unroll 1
        for (int sl = 0; sl < CH; ++sl) {
            const int so = sl * DD;

            // issue next-chunk staging loads at chunk start (drained ~1x/chunk)
            float4 pre0, pre1, pre2;
            const bool doPre = (sl == 0) && (tc + 1 < NCH);
            if (doPre) {
                const size_t nbg = base + (size_t)(tc + 1) * CH * DD;
                {
                    int seg = w * 3 + 0, arr = seg >> 3, sub = seg & 7;
                    pre0 = *(const float4*)((arr == 0 ? kphi : (arr == 1 ? qphi : x))
                                            + nbg + sub * 256 + lane * 4);
                }
                {
                    int seg = w * 3 + 1, arr = seg >> 3, sub = seg & 7;
                    pre1 = *(const float4*)((arr == 0 ? kphi : (arr == 1 ? qphi : x))
                                            + nbg + sub * 256 + lane * 4);
                }
                {
                    int seg = w * 3 + 2, arr = seg >> 3, sub = seg & 7;
                    pre2 = *(const float4*)((arr == 0 ? kphi : (arr == 1 ? qphi : x))
                                            + nbg + sub * 256 + lane * 4);
                }
            }

            // ---- phase 2 (row side): pred = M k, p = S v, cv = v.v ----
            v2f kk2[8];
            {
                const float4* k4 = (const float4*)(kcb + so);
                #pragma unroll
                for (int m = 0; m < 4; ++m) {
                    float4 v4 = k4[j + 8 * m];
                    kk2[2*m]     = mk2(v4.x, v4.y);
                    kk2[2*m + 1] = mk2(v4.z, v4.w);
                }
            }
            float pr0 = 0.f, pr1 = 0.f, pp0 = 0.f, pp1 = 0.f, cvp = 0.f;
            #pragma unroll
            for (int p = 0; p < 8; ++p) {
                v2f kv = kk2[p];
                pr0 = fmaf(M2[p].x,     kv.x, pr0); pr0 = fmaf(M2[p].y,     kv.y, pr0);
                pr1 = fmaf(M2[8+p].x,   kv.x, pr1); pr1 = fmaf(M2[8+p].y,   kv.y, pr1);
                pp0 = fmaf(S2[p].x,     kv.x, pp0); pp0 = fmaf(S2[p].y,     kv.y, pp0);
                pp1 = fmaf(S2[8+p].x,   kv.x, pp1); pp1 = fmaf(S2[8+p].y,   kv.y, pp1);
                cvp = fmaf(kv.x, kv.x, cvp);        cvp = fmaf(kv.y, kv.y, cvp);
            }
            pr0 = red8(pr0); pr1 = red8(pr1);
            pp0 = red8(pp0); pp1 = red8(pp1);
            const float cv = red8(cvp);
            const float2 xv = *(const float2*)&xcb[so + r0];
            const float u0 = pr0 - xv.x, u1 = pr1 - xv.y;
            const float p0 = pp0, p1 = pp1;
            if (j == 0) {
                *(float2*)&us[r0] = make_float2(u0, u1);
                *(float2*)&ps[r0] = make_float2(p0, p1);
            }
            __syncthreads();                               // barrier 1 (LDS only)

            // ---- phase 4 (col side): w = S^T u, h = S^T p, dots; ST update ----
            v2f uu2[8], pa2[8];
            {
                const float4* u4 = (const float4*)us;
                const float4* p4 = (const float4*)ps;
                #pragma unroll
                for (int m = 0; m < 4; ++m) {
                    float4 a4 = u4[j + 8 * m], b4 = p4[j + 8 * m];
                    uu2[2*m]     = mk2(a4.x, a4.y);
                    uu2[2*m + 1] = mk2(a4.z, a4.w);
                    pa2[2*m]     = mk2(b4.x, b4.y);
                    pa2[2*m + 1] = mk2(b4.z, b4.w);
                }
            }
            const float2 vc = *(const float2*)&kcb[so + r0];
            const v2f vcx = mk2(vc.x, vc.x), vcy = mk2(vc.y, vc.y);
            float w0 = 0.f, w1 = 0.f, h0 = 0.f, h1 = 0.f, cuup = 0.f, cupp = 0.f;
            #pragma unroll
            for (int p = 0; p < 8; ++p) {
                v2f uv = uu2[p], pv = pa2[p];
                v2f st0 = ST2[p], st1 = ST2[8 + p];
                w0 = fmaf(st0.x, uv.x, w0);   w0 = fmaf(st0.y, uv.y, w0);
                w1 = fmaf(st1.x, uv.x, w1);   w1 = fmaf(st1.y, uv.y, w1);
                h0 = fmaf(st0.x, pv.x, h0);   h0 = fmaf(st0.y, pv.y, h0);
                h1 = fmaf(st1.x, pv.x, h1);   h1 = fmaf(st1.y, pv.y, h1);
                cuup = fmaf(uv.x, uv.x, cuup); cuup = fmaf(uv.y, uv.y, cuup);
                cupp = fmaf(uv.x, pv.x, cupp); cupp = fmaf(uv.y, pv.y, cupp);
                ST2[p]     = fma2(av, st0, vcx * uv);      // old st used above only
                ST2[8 + p] = fma2(av, st1, vcy * uv);
            }
            w0 = red8(w0); w1 = red8(w1); h0 = red8(h0); h1 = red8(h1);
            const float cu  = red8(cuup);
            const float cup = red8(cupp);
            n2 = a2v * n2 + 2.0f * a * cup + cu * cv;      // ||S_t||_F^2 recurrence
            if (j == 0) {
                *(float2*)&wsv[r0] = make_float2(w0, w1);
                *(float2*)&hs[r0]  = make_float2(h0, h1);
            }
            // commit next-chunk staging to the other LDS buffer
            if (doPre) {
                float* kn = kc[cb ^ 1]; float* qn = qc[cb ^ 1]; float* xn = xc[cb ^ 1];
                {
                    int seg = w * 3 + 0, arr = seg >> 3, sub = seg & 7;
                    *(float4*)((arr == 0 ? kn : (arr == 1 ? qn : xn))
                               + sub * 256 + lane * 4) = pre0;
                }
                {
                    int seg = w * 3 + 1, arr = seg >> 3, sub = seg & 7;
                    *(float4*)((arr == 0 ? kn : (arr == 1 ? qn : xn))
                               + sub * 256 + lane * 4) = pre1;
                }
                {
                    int seg = w * 3 + 2, arr = seg >> 3, sub = seg & 7;
                    *(float4*)((arr == 0 ? kn : (arr == 1 ? qn : xn))
                               + sub * 256 + lane * 4) = pre2;
                }
            }
            __syncthreads();                               // barrier 2 (LDS only*)

            // ---- phase 6 (row side): g = S w; rank-3 A; S, M updates; y = M q ----
            v2f ww2[8], hh2[8], qq2[8];
            {
                const float4* w4 = (const float4*)wsv;
                const float4* h4 = (const float4*)hs;
                const float4* q4 = (const float4*)(qcb + so);
                #pragma unroll
                for (int m = 0; m < 4; ++m) {
                    float4 a4 = w4[j + 8 * m], b4 = h4[j + 8 * m], c4v = q4[j + 8 * m];
                    ww2[2*m]     = mk2(a4.x, a4.y);
                    ww2[2*m + 1] = mk2(a4.z, a4.w);
                    hh2[2*m]     = mk2(b4.x, b4.y);
                    hh2[2*m + 1] = mk2(b4.z, b4.w);
                    qq2[2*m]     = mk2(c4v.x, c4v.y);
                    qq2[2*m + 1] = mk2(c4v.z, c4v.w);
                }
            }
            float g0 = 0.f, g1 = 0.f;
            #pragma unroll
            for (int p = 0; p < 8; ++p) {
                v2f wv = ww2[p];
                g0 = fmaf(S2[p].x,   wv.x, g0); g0 = fmaf(S2[p].y,   wv.y, g0);
                g1 = fmaf(S2[8+p].x, wv.x, g1); g1 = fmaf(S2[8+p].y, wv.y, g1);
            }
            g0 = red8(g0); g1 = red8(g1);

            const float rho0 = a2v * g0 + a * cu * p0 + (a * cup + cv * cu) * u0;
            const float rho1 = a2v * g1 + a * cu * p1 + (a * cup + cv * cu) * u1;
            const float sg0  = a2v * p0 + a * cv * u0;
            const float sg1  = a2v * p1 + a * cv * u1;
            const float ta0  = a2v * u0, ta1 = a2v * u1;
            const float nrm  = sqrtf(fmaxf(n2, 0.f)) + 1e-6f;
            const float rn   = 1.0f / nrm;
            const float c1   = -0.015f * rn;    // 0.99M - 0.01*(1.5 S/n - 0.5 A/n^3)
            const float c2   = 0.005f * rn * rn * rn;

            const v2f u0v = mk2(u0, u0),   u1v = mk2(u1, u1);
            const v2f r0v = mk2(rho0, rho0), r1v = mk2(rho1, rho1);
            const v2f s0v = mk2(sg0, sg0), s1v = mk2(sg1, sg1);
            const v2f t0v = mk2(ta0, ta0), t1v = mk2(ta1, ta1);
            const v2f a3p = mk2(a3v, a3v);
            const v2f c9p = mk2(0.99f, 0.99f);
            const v2f c1p = mk2(c1, c1), c2p = mk2(c2, c2);

            float y0 = 0.f, y1 = 0.f;
            #pragma unroll
            for (int p = 0; p < 8; ++p) {
                v2f kv = kk2[p], wv = ww2[p], hv = hh2[p], qv = qq2[p];
                S2[p]     = fma2(av, S2[p],     u0v * kv);
                S2[8 + p] = fma2(av, S2[8 + p], u1v * kv);
                A2[p]     = fma2(a3p, A2[p],
                                 fma2(r0v, kv, fma2(s0v, wv, t0v * hv)));
                A2[8 + p] = fma2(a3p, A2[8 + p],
                                 fma2(r1v, kv, fma2(s1v, wv, t1v * hv)));
                M2[p]     = fma2(c9p, M2[p],     fma2(c1p, S2[p],     c2p * A2[p]));
                M2[8 + p] = fma2(c9p, M2[8 + p], fma2(c1p, S2[8 + p], c2p * A2[8 + p]));
                y0 = fmaf(M2[p].x,   qv.x, y0); y0 = fmaf(M2[p].y,   qv.y, y0);
                y1 = fmaf(M2[8+p].x, qv.x, y1); y1 = fmaf(M2[8+p].y, qv.y, y1);
            }
            y0 = red8(y0); y1 = red8(y1);
            if (j == 0)
                *(float2*)&yc[so + r0] = make_float2(y0, y1);
        }

        // chunk end: flush yc -> ys (one float4 per thread)
        __syncthreads();
        float4 yv = *(float4*)&yc[tid * 4];
        *(float4*)(ys + base + (size_t)tc * CH * DD + tid * 4) = yv;
    }
}

// ---------------- epilogue: out = ys @ Wout^T + bout ---------------------------
__global__ __launch_bounds__(128) void epilogue_kernel(
        const float* __restrict__ ys, const float* __restrict__ WoutT,
        const float* __restrict__ bout, float* __restrict__ out) {
    const int row0 = blockIdx.x * 8;
    const int e = threadIdx.x;
    __shared__ float yr[8][DD];
    #pragma unroll
    for (int rr = 0; rr < 8; ++rr)
        yr[rr][e] = ys[(size_t)(row0 + rr) * DD + e];
    __syncthreads();
    float acc[8] = {0,0,0,0,0,0,0,0};
    #pragma unroll 4
    for (int d = 0; d < DD; ++d) {
        float w = WoutT[d * DD + e];
        #pragma unroll
        for (int rr = 0; rr < 8; ++rr) acc[rr] = fmaf(yr[rr][d], w, acc[rr]);
    }
    const float bo = bout[e];
    #pragma unroll
    for (int rr = 0; rr < 8; ++rr)
        out[(size_t)(row0 + rr) * DD + e] = acc[rr] + bo;
}

extern "C" void kernel_launch(void* const* d_in, const int* in_sizes, int n_in,
                              void* d_out, int out_size, void* d_ws, size_t ws_size,
                              hipStream_t stream) {
    const float* x        = (const float*)d_in[0];
    const float* Wq       = (const float*)d_in[1];
    const float* Wk       = (const float*)d_in[2];
    const float* P0       = (const float*)d_in[3];
    const float* M0       = (const float*)d_in[4];
    const float* S0       = (const float*)d_in[5];
    const float* log_gain = (const float*)d_in[6];
    const float* coeffs   = (const float*)d_in[7];
    const float* Wout     = (const float*)d_in[8];
    const float* bout     = (const float*)d_in[9];
    float* out = (float*)d_out;

    float* ws    = (float*)d_ws;
    float* WqT   = ws;                      // 16384
    float* WkT   = ws + 16384;              // 16384
    float* WoutT = ws + 32768;              // 16384
    float* kphi  = ws + 49152;              // B*L*D each below
    float* qphi  = kphi + (size_t)BB * LL * DD;
    float* ysb   = qphi + (size_t)BB * LL * DD;

    hipLaunchKernelGGL(transpose3_kernel, dim3(3), dim3(256), 0, stream,
                       Wq, Wk, Wout, WqT, WkT, WoutT);
    hipLaunchKernelGGL(prologue_kernel, dim3(BB * LL / 8), dim3(128), 0, stream,
                       x, WqT, WkT, P0, log_gain, coeffs, kphi, qphi);
    hipLaunchKernelGGL(scan_kernel, dim3(BB), dim3(512), 0, stream,
                       kphi, qphi, x, M0, S0, ysb);
    hipLaunchKernelGGL(epilogue_kernel, dim3(BB * LL / 8), dim3(128), 0, stream,
                       ysb, WoutT, bout, out);
}

// Round 16
// 1288.860 us; speedup vs baseline: 2.7930x; 1.1687x over previous
//
#include <hip/hip_runtime.h>

#define BB 16
#define LL 512
#define DD 128
#define CH 16
#define NCH (LL / CH)

typedef float v2f __attribute__((ext_vector_type(2)));
__device__ __forceinline__ v2f mk2(float x, float y) { v2f r; r.x = x; r.y = y; return r; }
__device__ __forceinline__ v2f fma2(v2f a, v2f b, v2f c) {
    return __builtin_elementwise_fma(a, b, c);   // v_pk_fma_f32
}

// 8-lane all-reduce sum (lanes within a DPP half-row), pure VALU:
// quad xor1, quad xor2, then half-row mirror pairs the two quads.
__device__ __forceinline__ float red8(float v) {
    v += __int_as_float(__builtin_amdgcn_update_dpp(
            0, __float_as_int(v), 0xB1, 0xF, 0xF, true));
    v += __int_as_float(__builtin_amdgcn_update_dpp(
            0, __float_as_int(v), 0x4E, 0xF, 0xF, true));
    v += __int_as_float(__builtin_amdgcn_update_dpp(
            0, __float_as_int(v), 0x141, 0xF, 0xF, true));
    return v;
}

#define SCAN_REGS __attribute__((amdgpu_waves_per_eu(2, 2)))

// ---------------- transpose Wq, Wk, Wout (once per call, tiny) ----------------
__global__ void transpose3_kernel(const float* __restrict__ Wq,
                                  const float* __restrict__ Wk,
                                  const float* __restrict__ Wout,
                                  float* __restrict__ WqT,
                                  float* __restrict__ WkT,
                                  float* __restrict__ WoutT) {
    const float* src; float* dst;
    if (blockIdx.x == 0)      { src = Wq;   dst = WqT;   }
    else if (blockIdx.x == 1) { src = Wk;   dst = WkT;   }
    else                      { src = Wout; dst = WoutT; }
    for (int idx = threadIdx.x; idx < DD * DD; idx += blockDim.x) {
        int r = idx >> 7, c = idx & 127;
        dst[c * DD + r] = src[idx];
    }
}

// ---------------- prologue: q/k projections, k-normalize, P0 rotation, poly ----
__global__ __launch_bounds__(128) void prologue_kernel(
        const float* __restrict__ x, const float* __restrict__ WqT,
        const float* __restrict__ WkT, const float* __restrict__ P0,
        const float* __restrict__ log_gain, const float* __restrict__ coeffs,
        float* __restrict__ kphi, float* __restrict__ qphi) {
    const int row0 = blockIdx.x * 8;
    const int e = threadIdx.x;
    __shared__ float xs[8][DD];
    __shared__ float qrow[8][DD];
    __shared__ float wred[8][2];

    #pragma unroll
    for (int rr = 0; rr < 8; ++rr)
        xs[rr][e] = x[(size_t)(row0 + rr) * DD + e];
    __syncthreads();

    float aq[8] = {0,0,0,0,0,0,0,0}, ak[8] = {0,0,0,0,0,0,0,0};
    #pragma unroll 4
    for (int d = 0; d < DD; ++d) {
        float wq = WqT[d * DD + e];
        float wk = WkT[d * DD + e];
        #pragma unroll
        for (int rr = 0; rr < 8; ++rr) {
            float xv = xs[rr][d];
            aq[rr] = fmaf(xv, wq, aq[rr]);
            ak[rr] = fmaf(xv, wk, ak[rr]);
        }
    }
    const int lane = threadIdx.x & 63, wv = threadIdx.x >> 6;
    #pragma unroll
    for (int rr = 0; rr < 8; ++rr) {
        float s = ak[rr] * ak[rr];
        #pragma unroll
        for (int m = 1; m <= 32; m <<= 1) s += __shfl_xor(s, m);
        if (lane == 0) wred[rr][wv] = s;
    }
    __syncthreads();
    const float c0 = coeffs[0], c1v = coeffs[1];
    #pragma unroll
    for (int rr = 0; rr < 8; ++rr) {
        float s = wred[rr][0] + wred[rr][1];
        float kn = ak[rr] / fmaxf(sqrtf(s), 1e-12f);
        kphi[(size_t)(row0 + rr) * DD + e] = c0 * kn + c1v * kn * kn;
        qrow[rr][e] = aq[rr];
    }
    __syncthreads();
    float acc[8] = {0,0,0,0,0,0,0,0};
    #pragma unroll 4
    for (int d = 0; d < DD; ++d) {
        float pv = P0[d * DD + e];
        #pragma unroll
        for (int rr = 0; rr < 8; ++rr) acc[rr] = fmaf(qrow[rr][d], pv, acc[rr]);
    }
    const float g = expf(log_gain[e]);
    #pragma unroll
    for (int rr = 0; rr < 8; ++rr) {
        float qa = tanhf(g * acc[rr]);
        qphi[(size_t)(row0 + rr) * DD + e] = c0 * qa + c1v * qa * qa;
    }
}

// ---------------- main sequential scan: one block per batch --------------------
// R15 champion (packed elementwise state updates, chunked LDS staging,
// vmem-free per-step barriers) + ONE change: reduction accumulators are also
// packed (v2f chains, horizontal .x+.y add before red8) — cuts the remaining
// ~240 scalar reduction fmas/thread/step to ~120 pk-fma + 13 adds (~23% of
// VALU issue). Accumulators are loop-TRANSIENT (die at red8, nothing new
// lives across a barrier — R10's regression came from cross-barrier holds,
// not transient accumulators). Summation order changes (pairwise) -> absmax
// shifts slightly, well under threshold.
// Thread (g = tid>>3, j = tid&7): rows {2g,2g+1}; interleaved column set
// col(m,l) = 4j + 32m + l -> conflict-free unpadded vector reads.
// A = S S^T S via exact rank-3 recurrence; ||S||_F^2 via scalar recurrence.
__global__ SCAN_REGS __launch_bounds__(512)
void scan_kernel(
        const float* __restrict__ kphi, const float* __restrict__ qphi,
        const float* __restrict__ x, const float* __restrict__ M0,
        const float* __restrict__ S0, float* __restrict__ ys) {
    const int b    = blockIdx.x;
    const int tid  = threadIdx.x;
    const int j    = tid & 7;
    const int g    = tid >> 3;
    const int r0   = 2 * g;
    const int w    = tid >> 6;
    const int lane = tid & 63;

    __shared__ __align__(16) float kc[2][CH * DD];
    __shared__ __align__(16) float qc[2][CH * DD];
    __shared__ __align__(16) float xc[2][CH * DD];
    __shared__ __align__(16) float yc[CH * DD];
    __shared__ __align__(16) float us[DD], ps[DD], wsv[DD], hs[DD];
    __shared__ float red[64];
    __shared__ float n2sh;

    // state as column-pairs: index p<8 = row r0, p in [8,16) = row r0+1
    v2f S2[16], ST2[16], A2[16], M2[16];
    {
        const float4* S04 = (const float4*)S0;
        const float4* M04 = (const float4*)M0;
        #pragma unroll
        for (int rl = 0; rl < 2; ++rl)
            #pragma unroll
            for (int m = 0; m < 4; ++m) {
                int f4 = (r0 + rl) * 32 + j + 8 * m;
                float4 s4 = S04[f4], m4 = M04[f4];
                int p = rl * 8 + 2 * m;
                S2[p]     = mk2(s4.x, s4.y);
                S2[p + 1] = mk2(s4.z, s4.w);
                M2[p]     = mk2(m4.x, m4.y);
                M2[p + 1] = mk2(m4.z, m4.w);
            }
        #pragma unroll
        for (int rl = 0; rl < 2; ++rl)
            #pragma unroll
            for (int m = 0; m < 4; ++m) {
                int p = rl * 8 + 2 * m;
                ST2[p]     = mk2(S0[(size_t)(4*j + 32*m + 0) * DD + r0 + rl],
                                 S0[(size_t)(4*j + 32*m + 1) * DD + r0 + rl]);
                ST2[p + 1] = mk2(S0[(size_t)(4*j + 32*m + 2) * DD + r0 + rl],
                                 S0[(size_t)(4*j + 32*m + 3) * DD + r0 + rl]);
            }
        #pragma unroll
        for (int p = 0; p < 16; ++p) A2[p] = mk2(0.f, 0.f);  // exact: S0 == 0
    }

    // ||S0||^2 block reduction
    float sp = 0.f;
    #pragma unroll
    for (int p = 0; p < 16; ++p) {
        sp = fmaf(S2[p].x, S2[p].x, sp);
        sp = fmaf(S2[p].y, S2[p].y, sp);
    }
    sp = red8(sp);
    if (j == 0) red[g] = sp;

    const size_t base = (size_t)b * LL * DD;

    // preload chunk 0 (each wave copies 3 x 1KB segments)
    #pragma unroll
    for (int i = 0; i < 3; ++i) {
        int seg = w * 3 + i, arr = seg >> 3, sub = seg & 7;
        const float* sp0 = (arr == 0 ? kphi : (arr == 1 ? qphi : x))
                           + base + sub * 256 + lane * 4;
        float* dp = (arr == 0 ? kc[0] : (arr == 1 ? qc[0] : xc[0]))
                    + sub * 256 + lane * 4;
        *(float4*)dp = *(const float4*)sp0;
    }
    __syncthreads();
    if (tid < 64) {
        float s = red[tid];
        #pragma unroll
        for (int m = 1; m <= 32; m <<= 1) s += __shfl_xor(s, m);
        if (tid == 0) n2sh = s;
    }
    __syncthreads();
    float n2 = n2sh;

    const float a = 0.9f, a2v = 0.81f, a3v = 0.729f;
    const v2f av = mk2(a, a);

    #pragma unroll 1
    for (int tc = 0; tc < NCH; ++tc) {
        const int cb = tc & 1;
        const float* kcb = kc[cb];
        const float* qcb = qc[cb];
        const float* xcb = xc[cb];

        #pragma unroll 1
        for (int sl = 0; sl < CH; ++sl) {
            const int so = sl * DD;

            // issue next-chunk staging loads at chunk start (drained ~1x/chunk)
            float4 pre0, pre1, pre2;
            const bool doPre = (sl == 0) && (tc + 1 < NCH);
            if (doPre) {
                const size_t nbg = base + (size_t)(tc + 1) * CH * DD;
                {
                    int seg = w * 3 + 0, arr = seg >> 3, sub = seg & 7;
                    pre0 = *(const float4*)((arr == 0 ? kphi : (arr == 1 ? qphi : x))
                                            + nbg + sub * 256 + lane * 4);
                }
                {
                    int seg = w * 3 + 1, arr = seg >> 3, sub = seg & 7;
                    pre1 = *(const float4*)((arr == 0 ? kphi : (arr == 1 ? qphi : x))
                                            + nbg + sub * 256 + lane * 4);
                }
                {
                    int seg = w * 3 + 2, arr = seg >> 3, sub = seg & 7;
                    pre2 = *(const float4*)((arr == 0 ? kphi : (arr == 1 ? qphi : x))
                                            + nbg + sub * 256 + lane * 4);
                }
            }

            // ---- phase 2 (row side): pred = M k, p = S v, cv = v.v ----
            v2f kk2[8];
            {
                const float4* k4 = (const float4*)(kcb + so);
                #pragma unroll
                for (int m = 0; m < 4; ++m) {
                    float4 v4 = k4[j + 8 * m];
                    kk2[2*m]     = mk2(v4.x, v4.y);
                    kk2[2*m + 1] = mk2(v4.z, v4.w);
                }
            }
            v2f pr0v = mk2(0.f, 0.f), pr1v = mk2(0.f, 0.f);
            v2f pp0v = mk2(0.f, 0.f), pp1v = mk2(0.f, 0.f);
            v2f cvv  = mk2(0.f, 0.f);
            #pragma unroll
            for (int p = 0; p < 8; ++p) {
                v2f kv = kk2[p];
                pr0v = fma2(M2[p],     kv, pr0v);
                pr1v = fma2(M2[8 + p], kv, pr1v);
                pp0v = fma2(S2[p],     kv, pp0v);
                pp1v = fma2(S2[8 + p], kv, pp1v);
                cvv  = fma2(kv, kv, cvv);
            }
            float pr0 = red8(pr0v.x + pr0v.y);
            float pr1 = red8(pr1v.x + pr1v.y);
            float pp0 = red8(pp0v.x + pp0v.y);
            float pp1 = red8(pp1v.x + pp1v.y);
            const float cv = red8(cvv.x + cvv.y);
            const float2 xv = *(const float2*)&xcb[so + r0];
            const float u0 = pr0 - xv.x, u1 = pr1 - xv.y;
            const float p0 = pp0, p1 = pp1;
            if (j == 0) {
                *(float2*)&us[r0] = make_float2(u0, u1);
                *(float2*)&ps[r0] = make_float2(p0, p1);
            }
            __syncthreads();                               // barrier 1 (LDS only)

            // ---- phase 4 (col side): w = S^T u, h = S^T p, dots; ST update ----
            v2f uu2[8], pa2[8];
            {
                const float4* u4 = (const float4*)us;
                const float4* p4 = (const float4*)ps;
                #pragma unroll
                for (int m = 0; m < 4; ++m) {
                    float4 a4 = u4[j + 8 * m], b4 = p4[j + 8 * m];
                    uu2[2*m]     = mk2(a4.x, a4.y);
                    uu2[2*m + 1] = mk2(a4.z, a4.w);
                    pa2[2*m]     = mk2(b4.x, b4.y);
                    pa2[2*m + 1] = mk2(b4.z, b4.w);
                }
            }
            const float2 vc = *(const float2*)&kcb[so + r0];
            const v2f vcx = mk2(vc.x, vc.x), vcy = mk2(vc.y, vc.y);
            v2f w0v = mk2(0.f, 0.f), w1v = mk2(0.f, 0.f);
            v2f h0v = mk2(0.f, 0.f), h1v = mk2(0.f, 0.f);
            v2f cuv = mk2(0.f, 0.f), cupv = mk2(0.f, 0.f);
            #pragma unroll
            for (int p = 0; p < 8; ++p) {
                v2f uv = uu2[p], pv = pa2[p];
                v2f st0 = ST2[p], st1 = ST2[8 + p];
                w0v  = fma2(st0, uv, w0v);
                w1v  = fma2(st1, uv, w1v);
                h0v  = fma2(st0, pv, h0v);
                h1v  = fma2(st1, pv, h1v);
                cuv  = fma2(uv, uv, cuv);
                cupv = fma2(uv, pv, cupv);
                ST2[p]     = fma2(av, st0, vcx * uv);      // old st used above only
                ST2[8 + p] = fma2(av, st1, vcy * uv);
            }
            float w0 = red8(w0v.x + w0v.y);
            float w1 = red8(w1v.x + w1v.y);
            float h0 = red8(h0v.x + h0v.y);
            float h1 = red8(h1v.x + h1v.y);
            const float cu  = red8(cuv.x + cuv.y);
            const float cup = red8(cupv.x + cupv.y);
            n2 = a2v * n2 + 2.0f * a * cup + cu * cv;      // ||S_t||_F^2 recurrence
            if (j == 0) {
                *(float2*)&wsv[r0] = make_float2(w0, w1);
                *(float2*)&hs[r0]  = make_float2(h0, h1);
            }
            // commit next-chunk staging to the other LDS buffer
            if (doPre) {
                float* kn = kc[cb ^ 1]; float* qn = qc[cb ^ 1]; float* xn = xc[cb ^ 1];
                {
                    int seg = w * 3 + 0, arr = seg >> 3, sub = seg & 7;
                    *(float4*)((arr == 0 ? kn : (arr == 1 ? qn : xn))
                               + sub * 256 + lane * 4) = pre0;
                }
                {
                    int seg = w * 3 + 1, arr = seg >> 3, sub = seg & 7;
                    *(float4*)((arr == 0 ? kn : (arr == 1 ? qn : xn))
                               + sub * 256 + lane * 4) = pre1;
                }
                {
                    int seg = w * 3 + 2, arr = seg >> 3, sub = seg & 7;
                    *(float4*)((arr == 0 ? kn : (arr == 1 ? qn : xn))
                               + sub * 256 + lane * 4) = pre2;
                }
            }
            __syncthreads();                               // barrier 2 (LDS only*)

            // ---- phase 6 (row side): g = S w; rank-3 A; S, M updates; y = M q ----
            v2f ww2[8], hh2[8], qq2[8];
            {
                const float4* w4 = (const float4*)wsv;
                const float4* h4 = (const float4*)hs;
                const float4* q4 = (const float4*)(qcb + so);
                #pragma unroll
                for (int m = 0; m < 4; ++m) {
                    float4 a4 = w4[j + 8 * m], b4 = h4[j + 8 * m], c4v = q4[j + 8 * m];
                    ww2[2*m]     = mk2(a4.x, a4.y);
                    ww2[2*m + 1] = mk2(a4.z, a4.w);
                    hh2[2*m]     = mk2(b4.x, b4.y);
                    hh2[2*m + 1] = mk2(b4.z, b4.w);
                    qq2[2*m]     = mk2(c4v.x, c4v.y);
                    qq2[2*m + 1] = mk2(c4v.z, c4v.w);
                }
            }
            v2f g0v = mk2(0.f, 0.f), g1v = mk2(0.f, 0.f);
            #pragma unroll
            for (int p = 0; p < 8; ++p) {
                v2f wv = ww2[p];
                g0v = fma2(S2[p],     wv, g0v);
                g1v = fma2(S2[8 + p], wv, g1v);
            }
            float g0 = red8(g0v.x + g0v.y);
            float g1 = red8(g1v.x + g1v.y);

            const float rho0 = a2v * g0 + a * cu * p0 + (a * cup + cv * cu) * u0;
            const float rho1 = a2v * g1 + a * cu * p1 + (a * cup + cv * cu) * u1;
            const float sg0  = a2v * p0 + a * cv * u0;
            const float sg1  = a2v * p1 + a * cv * u1;
            const float ta0  = a2v * u0, ta1 = a2v * u1;
            const float nrm  = sqrtf(fmaxf(n2, 0.f)) + 1e-6f;
            const float rn   = 1.0f / nrm;
            const float c1   = -0.015f * rn;    // 0.99M - 0.01*(1.5 S/n - 0.5 A/n^3)
            const float c2   = 0.005f * rn * rn * rn;

            const v2f u0v = mk2(u0, u0),   u1v = mk2(u1, u1);
            const v2f r0v = mk2(rho0, rho0), r1v = mk2(rho1, rho1);
            const v2f s0v = mk2(sg0, sg0), s1v = mk2(sg1, sg1);
            const v2f t0v = mk2(ta0, ta0), t1v = mk2(ta1, ta1);
            const v2f a3p = mk2(a3v, a3v);
            const v2f c9p = mk2(0.99f, 0.99f);
            const v2f c1p = mk2(c1, c1), c2p = mk2(c2, c2);

            v2f y0v = mk2(0.f, 0.f), y1v = mk2(0.f, 0.f);
            #pragma unroll
            for (int p = 0; p < 8; ++p) {
                v2f kv = kk2[p], wv = ww2[p], hv = hh2[p], qv = qq2[p];
                S2[p]     = fma2(av, S2[p],     u0v * kv);
                S2[8 + p] = fma2(av, S2[8 + p], u1v * kv);
                A2[p]     = fma2(a3p, A2[p],
                                 fma2(r0v, kv, fma2(s0v, wv, t0v * hv)));
                A2[8 + p] = fma2(a3p, A2[8 + p],
                                 fma2(r1v, kv, fma2(s1v, wv, t1v * hv)));
                M2[p]     = fma2(c9p, M2[p],     fma2(c1p, S2[p],     c2p * A2[p]));
                M2[8 + p] = fma2(c9p, M2[8 + p], fma2(c1p, S2[8 + p], c2p * A2[8 + p]));
                y0v = fma2(M2[p],     qv, y0v);
                y1v = fma2(M2[8 + p], qv, y1v);
            }
            float y0 = red8(y0v.x + y0v.y);
            float y1 = red8(y1v.x + y1v.y);
            if (j == 0)
                *(float2*)&yc[so + r0] = make_float2(y0, y1);
        }

        // chunk end: flush yc -> ys (one float4 per thread)
        __syncthreads();
        float4 yv = *(float4*)&yc[tid * 4];
        *(float4*)(ys + base + (size_t)tc * CH * DD + tid * 4) = yv;
    }
}

// ---------------- epilogue: out = ys @ Wout^T + bout ---------------------------
__global__ __launch_bounds__(128) void epilogue_kernel(
        const float* __restrict__ ys, const float* __restrict__ WoutT,
        const float* __restrict__ bout, float* __restrict__ out) {
    const int row0 = blockIdx.x * 8;
    const int e = threadIdx.x;
    __shared__ float yr[8][DD];
    #pragma unroll
    for (int rr = 0; rr < 8; ++rr)
        yr[rr][e] = ys[(size_t)(row0 + rr) * DD + e];
    __syncthreads();
    float acc[8] = {0,0,0,0,0,0,0,0};
    #pragma unroll 4
    for (int d = 0; d < DD; ++d) {
        float w = WoutT[d * DD + e];
        #pragma unroll
        for (int rr = 0; rr < 8; ++rr) acc[rr] = fmaf(yr[rr][d], w, acc[rr]);
    }
    const float bo = bout[e];
    #pragma unroll
    for (int rr = 0; rr < 8; ++rr)
        out[(size_t)(row0 + rr) * DD + e] = acc[rr] + bo;
}

extern "C" void kernel_launch(void* const* d_in, const int* in_sizes, int n_in,
                              void* d_out, int out_size, void* d_ws, size_t ws_size,
                              hipStream_t stream) {
    const float* x        = (const float*)d_in[0];
    const float* Wq       = (const float*)d_in[1];
    const float* Wk       = (const float*)d_in[2];
    const float* P0       = (const float*)d_in[3];
    const float* M0       = (const float*)d_in[4];
    const float* S0       = (const float*)d_in[5];
    const float* log_gain = (const float*)d_in[6];
    const float* coeffs   = (const float*)d_in[7];
    const float* Wout     = (const float*)d_in[8];
    const float* bout     = (const float*)d_in[9];
    float* out = (float*)d_out;

    float* ws    = (float*)d_ws;
    float* WqT   = ws;                      // 16384
    float* WkT   = ws + 16384;              // 16384
    float* WoutT = ws + 32768;              // 16384
    float* kphi  = ws + 49152;              // B*L*D each below
    float* qphi  = kphi + (size_t)BB * LL * DD;
    float* ysb   = qphi + (size_t)BB * LL * DD;

    hipLaunchKernelGGL(transpose3_kernel, dim3(3), dim3(256), 0, stream,
                       Wq, Wk, Wout, WqT, WkT, WoutT);
    hipLaunchKernelGGL(prologue_kernel, dim3(BB * LL / 8), dim3(128), 0, stream,
                       x, WqT, WkT, P0, log_gain, coeffs, kphi, qphi);
    hipLaunchKernelGGL(scan_kernel, dim3(BB), dim3(512), 0, stream,
                       kphi, qphi, x, M0, S0, ysb);
    hipLaunchKernelGGL(epilogue_kernel, dim3(BB * LL / 8), dim3(128), 0, stream,
                       ysb, WoutT, bout, out);
}